// Round 10
// baseline (23229.044 us; speedup 1.0000x reference)
//
#include <hip/hip_runtime.h>
#include <hip/hip_fp16.h>
#include <stdint.h>

// LSTM, E=2048, B=2, T=2048, ALL I/O float32 (per reference dtypes).
// For t>=1 input==h, so gates = h @ (W_ih+W_hh)^T + (b_ih+b_hh).
// v11: BATCH-SPLIT blocks (the two batches are independent recurrences).
//  - 256 blocks x 1024 threads; block = (batch bb = blk&1, 16 elems).
//    Per-thread: 8 gate-rows x 16 k = 64 half2 weights (v4's count -> no
//    spill; 1024 thr = 4 waves/SIMD = 128-VGPR cap, budget ~110).
//  - Consumer poll: ONE dwordx4 per lane (2 chunks, elements 2*tid,2*tid+1)
//    = 16 KB/block/round; total fabric burst 4 MB/round (HALF of v4's 8MB
//    -- poll-queueing inflated RTT was the modeled residual cost).
//  - Only 128 producers per consumer -> smaller E[max] publish jitter.
//  - Tail: wave0's 64 lanes each finish ONE gate-row (1 transcendental,
//    tanh via 2*sig(2s)-1), 3 shfl gathers; publish = lanes 0-15 = ONE
//    coalesced 128 B store (v9 law: publish must not fragment).
//  - Wave-locality preserved: wave wv deposits exactly its FMA k-slice
//    [wv*128,+128) (lanes tid in [wv*64,+64) own e=2*tid,2*tid+1) ->
//    lgkmcnt-only deposit sync still valid, ONE __syncthreads/step.
//  - h LDS: 20-float-padded 16-slices (conflict-free b128 reads);
//    pls[parity][wave][68] (b128 writes 2-way, b32 reads 2-way = free).
// Kept from v4: f16 packed weights (v_fma_mix), poll cadence = initial
// vmcnt(0) + sleep(1) + exec-masked reload (v6: pipelined no-sleep
// regresses), c-state in registers, sc0 sc1 LLC-direct exchange both
// sides, publish-before-seqout, fast sigmoid/tanh.
// Protocol: 8 B [tag|payload] chunks, tag-validated (poison 0xAAAAAAAA
// never matches tags 1..2047), relaxed, no fences.
// chk layout: [parity(2)][batch(2)][2048 elems] x 8 B = 64 KB.

#define E 2048
#define NBLK 256
#define NTHR 1024
#define SMEM_MAIN 18944        // hlds 10240 + pls 8704
#define SMEM_PROJ 131072

typedef uint32_t u32;
typedef unsigned long long u64;
typedef unsigned int u32x4 __attribute__((ext_vector_type(4)));

__device__ __forceinline__ float sigf(float x){
  return __builtin_amdgcn_rcpf(1.0f + __expf(-x));
}
__device__ __forceinline__ float tanhfast(float x){
  float e = __expf(2.0f * x);
  return 1.0f - 2.0f * __builtin_amdgcn_rcpf(e + 1.0f);
}

__global__ void __launch_bounds__(NTHR, 1) lstm_kernel(
    const float* __restrict__ xin, const float* __restrict__ Wih,
    const float* __restrict__ Whh, const float* __restrict__ bih,
    const float* __restrict__ bhh, u64* __restrict__ chk,
    float* __restrict__ seqout)
{
  extern __shared__ char smem[];
  float* hlds = (float*)smem;                 // 128 slices x 20 fl = 10240 B
  float* pls  = (float*)(smem + 10240);       // [2][16][68] fl = 8704 B

  const int tid  = threadIdx.x;
  const int blk  = blockIdx.x;
  const int bb   = blk & 1;                   // batch (interleaved over XCDs)
  const int e0   = (blk >> 1) << 4;           // first of 16 owned elems
  const int lane = tid & 63;
  const int wv   = tid >> 6;                  // wave 0..15, k-slice [wv*128,+128)
  const int rg   = lane >> 3;                 // row group: rows rg*8..rg*8+7
  const int ksl  = lane & 7;                  // 16-k sub-slice within wave
  const int slice = (wv << 3) + ksl;          // global 16-k slice 0..127
  const int k0   = slice << 4;

  // stage x (own batch) in the padded h layout
  for (int k = tid; k < E; k += NTHR)
    hlds[(k >> 4) * 20 + (k & 15)] = xin[bb * E + k];
  __syncthreads();

  const float* hp = hlds + slice * 20;        // own 16-k slice (padded)
  float4 xv0 = *(const float4*)(hp);
  float4 xv1 = *(const float4*)(hp + 4);
  float4 xv2 = *(const float4*)(hp + 8);
  float4 xv3 = *(const float4*)(hp + 12);

  // ---- fused: pack f16 Wc = Wih + Whh (8 rows x 16 k = 64 half2) AND
  //      compute t=0 gates = x @ W_ih^T in full fp32 ----
  __half2 wh[64];
  float acc[8];
  #pragma unroll
  for (int rr = 0; rr < 8; ++rr) acc[rr] = 0.0f;
  #pragma unroll
  for (int rr = 0; rr < 8; ++rr){
    const int r = (rg << 3) + rr;             // 0..63 = gate*16 + local elem
    const size_t grow = ((size_t)(r >> 4) << 11) + e0 + (r & 15);
    const float* pa = Wih + grow * E + k0;
    const float* pb = Whh + grow * E + k0;
    float4 a0 = *(const float4*)(pa);
    float4 a1 = *(const float4*)(pa + 4);
    float4 a2 = *(const float4*)(pa + 8);
    float4 a3 = *(const float4*)(pa + 12);
    float4 b0 = *(const float4*)(pb);
    float4 b1 = *(const float4*)(pb + 4);
    float4 b2 = *(const float4*)(pb + 8);
    float4 b3 = *(const float4*)(pb + 12);
    wh[(rr<<3)+0] = __halves2half2(__float2half_rn(a0.x+b0.x), __float2half_rn(a0.y+b0.y));
    wh[(rr<<3)+1] = __halves2half2(__float2half_rn(a0.z+b0.z), __float2half_rn(a0.w+b0.w));
    wh[(rr<<3)+2] = __halves2half2(__float2half_rn(a1.x+b1.x), __float2half_rn(a1.y+b1.y));
    wh[(rr<<3)+3] = __halves2half2(__float2half_rn(a1.z+b1.z), __float2half_rn(a1.w+b1.w));
    wh[(rr<<3)+4] = __halves2half2(__float2half_rn(a2.x+b2.x), __float2half_rn(a2.y+b2.y));
    wh[(rr<<3)+5] = __halves2half2(__float2half_rn(a2.z+b2.z), __float2half_rn(a2.w+b2.w));
    wh[(rr<<3)+6] = __halves2half2(__float2half_rn(a3.x+b3.x), __float2half_rn(a3.y+b3.y));
    wh[(rr<<3)+7] = __halves2half2(__float2half_rn(a3.z+b3.z), __float2half_rn(a3.w+b3.w));
    float a = acc[rr];
    a = fmaf(a0.x, xv0.x, a); a = fmaf(a0.y, xv0.y, a);
    a = fmaf(a0.z, xv0.z, a); a = fmaf(a0.w, xv0.w, a);
    a = fmaf(a1.x, xv1.x, a); a = fmaf(a1.y, xv1.y, a);
    a = fmaf(a1.z, xv1.z, a); a = fmaf(a1.w, xv1.w, a);
    a = fmaf(a2.x, xv2.x, a); a = fmaf(a2.y, xv2.y, a);
    a = fmaf(a2.z, xv2.z, a); a = fmaf(a2.w, xv2.w, a);
    a = fmaf(a3.x, xv3.x, a); a = fmaf(a3.y, xv3.y, a);
    a = fmaf(a3.z, xv3.z, a); a = fmaf(a3.w, xv3.w, a);
    acc[rr] = a;
  }

  // tail constants (wave 0): lane = row r; gate g = r>>4, elem le = r&15
  const size_t growt = ((size_t)(lane >> 4) << 11) + e0 + (lane & 15);
  const float br = bih[growt] + bhh[growt];
  float creg = 0.0f;                          // 4 identical copies per elem

  // poll mapping: lane owns elements 2*tid, 2*tid+1 (one dwordx4)
  const int dbase = (tid >> 3) * 20 + ((tid << 1) & 15);  // LDS deposit addr
  u64* const pchk = chk + ((size_t)bb << 11);
  const u64* const psrc = pchk + (tid << 1);

  for (int t = 0; t < 2048; ++t){
    // wave-level pre-reduce across the 8 k-sub-slices (ksl = lane bits 0..2)
    #pragma unroll
    for (int m = 1; m <= 4; m <<= 1){
      #pragma unroll
      for (int rr = 0; rr < 8; ++rr)
        acc[rr] += __shfl_xor(acc[rr], m, 64);
    }
    if (ksl == 0){                            // rows rg*8..+7 -> pls[wv][rg*8]
      float* pw = pls + (t & 1) * 1088 + wv * 68 + (rg << 3);
      *(float4*)(pw)     = make_float4(acc[0], acc[1], acc[2], acc[3]);
      *(float4*)(pw + 4) = make_float4(acc[4], acc[5], acc[6], acc[7]);
    }
    __syncthreads();                          // the ONLY barrier per step

    if (wv == 0){                             // 64 lanes: one gate-row each
      const float* rp = pls + (t & 1) * 1088 + lane;
      float s = br;
      #pragma unroll
      for (int w = 0; w < 16; ++w) s += rp[w * 68];
      const int g  = lane >> 4;
      const int le = lane & 15;
      const float arg = (g == 2) ? (s + s) : s;
      const float t0v = sigf(arg);
      const float nl  = (g == 2) ? (2.0f * t0v - 1.0f) : t0v;
      const float SI = __shfl(nl, le, 64);
      const float SF = __shfl(nl, 16 + le, 64);
      const float TG = __shfl(nl, 32 + le, 64);
      const float SO = __shfl(nl, 48 + le, 64);
      const float cn = SF * creg + SI * TG;
      const float hn = SO * tanhfast(cn);
      creg = cn;
      if (lane < 16){
        if (t < 2047){                        // publish FIRST: one 128B store
          const u64 pk = ((u64)(u32)(t + 1) << 32) | (u64)__float_as_uint(hn);
          u64* dst = pchk + (((t + 1) & 1) << 12) + e0 + lane;
          asm volatile("global_store_dwordx2 %0, %1, off sc0 sc1"
                       :: "v"(dst), "v"(pk) : "memory");
        }
        seqout[(((size_t)bb << 11) + (size_t)t) * E + e0 + lane] = hn;
      }
    }
    if (t == 2047) break;

    {                                         // poll: 1 dwordx4/lane, v4 cadence
      const u64* src = psrc + (((t + 1) & 1) << 12);
      const u32 tag = (u32)(t + 1);
      u32x4 q;                                // [pay0, tag0, pay1, tag1]
      asm volatile("global_load_dwordx4 %0, %1, off sc0 sc1"
                   : "=v"(q) : "v"(src) : "memory");
      asm volatile("s_waitcnt vmcnt(0)" ::: "memory");
      int pend = 3;
      for (;;){
        if ((pend & 1) && q.y == tag){ hlds[dbase]     = __uint_as_float(q.x); pend &= ~1; }
        if ((pend & 2) && q.w == tag){ hlds[dbase + 1] = __uint_as_float(q.z); pend &= ~2; }
        if (!pend) break;
        __builtin_amdgcn_s_sleep(1);
        if (pend){
          asm volatile("global_load_dwordx4 %0, %1, off sc0 sc1"
                       : "=v"(q) : "v"(src) : "memory");
        }
        asm volatile("s_waitcnt vmcnt(0)" ::: "memory");
      }
      // own ds_writes visible to all lanes of this wave (wave-synchronous)
      asm volatile("s_waitcnt lgkmcnt(0)" ::: "memory");
      __builtin_amdgcn_sched_barrier(0);
    }

    // compute acc(t+1): h(own 16-k slice, LDS) @ Wc^T (f16 regs)
    {
      float4 h0 = *(const float4*)(hp);
      float4 h1 = *(const float4*)(hp + 4);
      float4 h2 = *(const float4*)(hp + 8);
      float4 h3 = *(const float4*)(hp + 12);
      #pragma unroll
      for (int rr = 0; rr < 8; ++rr){
        const __half2* w = &wh[rr << 3];
        float a = 0.0f;
        a = fmaf(__low2float(w[0]), h0.x, a); a = fmaf(__high2float(w[0]), h0.y, a);
        a = fmaf(__low2float(w[1]), h0.z, a); a = fmaf(__high2float(w[1]), h0.w, a);
        a = fmaf(__low2float(w[2]), h1.x, a); a = fmaf(__high2float(w[2]), h1.y, a);
        a = fmaf(__low2float(w[3]), h1.z, a); a = fmaf(__high2float(w[3]), h1.w, a);
        a = fmaf(__low2float(w[4]), h2.x, a); a = fmaf(__high2float(w[4]), h2.y, a);
        a = fmaf(__low2float(w[5]), h2.z, a); a = fmaf(__high2float(w[5]), h2.w, a);
        a = fmaf(__low2float(w[6]), h3.x, a); a = fmaf(__high2float(w[6]), h3.y, a);
        a = fmaf(__low2float(w[7]), h3.z, a); a = fmaf(__high2float(w[7]), h3.w, a);
        acc[rr] = a;
      }
    }
  }
}

// In-place projection: out[row][n] = sum_k h[row][k]*Wout[n][k] + bout[n].
// Block owns 16 rows (f32-staged to LDS). v10-verified: 2 passes x 4 cols
// per thread -- each pair of broadcast LDS b128 reads feeds 32 FMAs.
__global__ void __launch_bounds__(256, 1) proj_kernel(
    float* __restrict__ io, const float* __restrict__ Wout,
    const float* __restrict__ bout)
{
  extern __shared__ char smem[];
  float* alds = (float*)smem;                  // 16 x 2048 fp32 = 131072 B
  const int tid = threadIdx.x;
  const size_t rbase = (size_t)blockIdx.x * 16 * E;

  for (int idx = tid; idx < 8192; idx += 256){
    float4 v = *(const float4*)(io + rbase + ((size_t)idx << 2));
    *(float4*)(alds + (idx << 2)) = v;
  }
  __syncthreads();

  for (int p = 0; p < 2; ++p){
    const int n0 = (p << 10) + tid;            // 4 columns: n0 + {0,256,512,768}
    const int n1 = n0 + 256;
    const int n2 = n0 + 512;
    const int n3 = n0 + 768;
    const float* wr0 = Wout + (size_t)n0 * E;
    const float* wr1 = Wout + (size_t)n1 * E;
    const float* wr2 = Wout + (size_t)n2 * E;
    const float* wr3 = Wout + (size_t)n3 * E;
    float acc0[16], acc1[16], acc2[16], acc3[16];
    #pragma unroll
    for (int m = 0; m < 16; ++m){
      acc0[m] = 0.0f; acc1[m] = 0.0f; acc2[m] = 0.0f; acc3[m] = 0.0f;
    }
    for (int kc = 0; kc < 256; ++kc){          // 8 k per iter
      const float4 a0v = *(const float4*)(wr0 + (kc << 3));
      const float4 a1v = *(const float4*)(wr0 + (kc << 3) + 4);
      const float4 b0v = *(const float4*)(wr1 + (kc << 3));
      const float4 b1v = *(const float4*)(wr1 + (kc << 3) + 4);
      const float4 c0v = *(const float4*)(wr2 + (kc << 3));
      const float4 c1v = *(const float4*)(wr2 + (kc << 3) + 4);
      const float4 d0v = *(const float4*)(wr3 + (kc << 3));
      const float4 d1v = *(const float4*)(wr3 + (kc << 3) + 4);
      const float* ap = alds + (kc << 3);
      #pragma unroll
      for (int m = 0; m < 16; ++m){
        const float* a = ap + (m << 11);
        float4 x0 = *(const float4*)(a);       // broadcast: all lanes same addr
        float4 x1 = *(const float4*)(a + 4);
        acc0[m] = fmaf(a0v.x, x0.x, acc0[m]); acc0[m] = fmaf(a0v.y, x0.y, acc0[m]);
        acc0[m] = fmaf(a0v.z, x0.z, acc0[m]); acc0[m] = fmaf(a0v.w, x0.w, acc0[m]);
        acc0[m] = fmaf(a1v.x, x1.x, acc0[m]); acc0[m] = fmaf(a1v.y, x1.y, acc0[m]);
        acc0[m] = fmaf(a1v.z, x1.z, acc0[m]); acc0[m] = fmaf(a1v.w, x1.w, acc0[m]);
        acc1[m] = fmaf(b0v.x, x0.x, acc1[m]); acc1[m] = fmaf(b0v.y, x0.y, acc1[m]);
        acc1[m] = fmaf(b0v.z, x0.z, acc1[m]); acc1[m] = fmaf(b0v.w, x0.w, acc1[m]);
        acc1[m] = fmaf(b1v.x, x1.x, acc1[m]); acc1[m] = fmaf(b1v.y, x1.y, acc1[m]);
        acc1[m] = fmaf(b1v.z, x1.z, acc1[m]); acc1[m] = fmaf(b1v.w, x1.w, acc1[m]);
        acc2[m] = fmaf(c0v.x, x0.x, acc2[m]); acc2[m] = fmaf(c0v.y, x0.y, acc2[m]);
        acc2[m] = fmaf(c0v.z, x0.z, acc2[m]); acc2[m] = fmaf(c0v.w, x0.w, acc2[m]);
        acc2[m] = fmaf(c1v.x, x1.x, acc2[m]); acc2[m] = fmaf(c1v.y, x1.y, acc2[m]);
        acc2[m] = fmaf(c1v.z, x1.z, acc2[m]); acc2[m] = fmaf(c1v.w, x1.w, acc2[m]);
        acc3[m] = fmaf(d0v.x, x0.x, acc3[m]); acc3[m] = fmaf(d0v.y, x0.y, acc3[m]);
        acc3[m] = fmaf(d0v.z, x0.z, acc3[m]); acc3[m] = fmaf(d0v.w, x0.w, acc3[m]);
        acc3[m] = fmaf(d1v.x, x1.x, acc3[m]); acc3[m] = fmaf(d1v.y, x1.y, acc3[m]);
        acc3[m] = fmaf(d1v.z, x1.z, acc3[m]); acc3[m] = fmaf(d1v.w, x1.w, acc3[m]);
      }
    }
    const float bo0 = bout[n0];
    const float bo1 = bout[n1];
    const float bo2 = bout[n2];
    const float bo3 = bout[n3];
    #pragma unroll
    for (int m = 0; m < 16; ++m){
      io[rbase + ((size_t)m << 11) + n0] = acc0[m] + bo0;
      io[rbase + ((size_t)m << 11) + n1] = acc1[m] + bo1;
      io[rbase + ((size_t)m << 11) + n2] = acc2[m] + bo2;
      io[rbase + ((size_t)m << 11) + n3] = acc3[m] + bo3;
    }
  }
}

extern "C" void kernel_launch(void* const* d_in, const int* in_sizes, int n_in,
                              void* d_out, int out_size, void* d_ws, size_t ws_size,
                              hipStream_t stream)
{
  const float* xin  = (const float*)d_in[0];
  const float* Wih  = (const float*)d_in[1];
  const float* Whh  = (const float*)d_in[2];
  const float* bih  = (const float*)d_in[3];
  const float* bhh  = (const float*)d_in[4];
  const float* Wout = (const float*)d_in[5];
  const float* bout = (const float*)d_in[6];
  float* out = (float*)d_out;

  // chunk buffer: [parity(2)][batch(2)][2048] x 8 B = 64 KB.
  // Poison 0xAAAAAAAA is never a valid tag (tags are 1..2047) -> no init pass.
  u64* chk = (u64*)d_ws;

  hipFuncSetAttribute((const void*)lstm_kernel,
                      hipFuncAttributeMaxDynamicSharedMemorySize, SMEM_MAIN);
  hipFuncSetAttribute((const void*)proj_kernel,
                      hipFuncAttributeMaxDynamicSharedMemorySize, SMEM_PROJ);

  void* args[] = { (void*)&xin, (void*)&Wih, (void*)&Whh, (void*)&bih, (void*)&bhh,
                   (void*)&chk, (void*)&out };
  hipLaunchCooperativeKernel((const void*)lstm_kernel, dim3(NBLK), dim3(NTHR),
                             args, SMEM_MAIN, stream);

  proj_kernel<<<256, 256, SMEM_PROJ, stream>>>(out, Wout, bout);
}

// Round 11
// 8080.553 us; speedup vs baseline: 2.8747x; 2.8747x over previous
//
#include <hip/hip_runtime.h>
#include <hip/hip_fp16.h>
#include <stdint.h>

// LSTM, E=2048, B=2, T=2048, ALL I/O float32 (per reference dtypes).
// For t>=1 input==h, so gates = h @ (W_ih+W_hh)^T + (b_ih+b_hh).
// v12 = lstm: v10 (anchor 7460us) + poll-reorder (issue reloads BEFORE
//       s_sleep: round period max(RTT,sleep) instead of sleep+RTT; same
//       traffic, same protocol)
//     + proj: PAIR-BLOCK f16-staged (Wout traffic halved, all CUs busy).
// v11 post-mortem: VGPR cap halves with waves/SIMD (512thr->128, 1024thr->64
//   measured); 1024-thr batch-split spilled (FETCH 19.3GB) -> topology dead.
// proj v12: proj is Wout-LLC-BW-bound (4.3GB/700us ~= 6.1TB/s ceiling).
//   Block pair (2b,2b+1) shares rows 32b..32b+31 (f16 in 128KB LDS); block
//   computes one 1024-col half -> Wout reads 2.05GB, 256 CUs busy,
//   per-thread LDS issue = v10. In-place pair race (partner writes cols the
//   other stages) is removed by copying seq to WORKSPACE first (33.5MB,
//   ~15us) and staging from the copy. Runtime-gated on ws_size; falls back
//   to v10's proven proj if workspace too small. f16 staging is ONE-SHOT
//   (no recurrence; v9 measured absmax 1.95e-3 < 1.1e-2 threshold).
// Kept lstm (v10/v4, verified 3x): f16 packed weights in VGPRs (v_fma_mix),
// fp32 h in padded LDS (stride 36), wave-local poll slice, vmcnt(0)+sleep
// cadence (v6: pipelined no-sleep regresses), lgkmcnt-only deposit sync,
// ONE __syncthreads/step, wave0 tail with single coalesced 128B publish
// (v9 law: publish must not fragment), c-state in registers, sc0 sc1
// LLC-direct exchange, publish-before-seqout. Protocol: 8B [tag|payload]
// chunks, tag-validated (poison 0xAAAAAAAA never matches tags 1..2047).

#define E 2048
#define NBLK 256
#define NTHR 512
#define HLDS_B 2304            // padded floats per batch: 64 slices * 36
#define PLS_STRIDE 20          // floats per row slot (16 used + 4 pad)
#define PLS_PAR 640            // floats per parity: 32 rows * 20
#define SMEM_MAIN 23680
#define SMEM_PROJ 131072

typedef uint32_t u32;
typedef unsigned long long u64;

__device__ __forceinline__ float sigf(float x){
  return __builtin_amdgcn_rcpf(1.0f + __expf(-x));
}
__device__ __forceinline__ float tanhfast(float x){
  // 1 - 2/(e^{2x}+1); exp overflow -> rcp(inf)=0 -> 1; underflow -> -1.
  float e = __expf(2.0f * x);
  return 1.0f - 2.0f * __builtin_amdgcn_rcpf(e + 1.0f);
}

// one row x 8 k, both batches: 16 FMAs from 4 packed-f16 weight pairs
#define ROWFMA8(W0, W1, W2, W3, A0, A1) \
  A0 = fmaf(__low2float(W0),  p0.x, A0); A0 = fmaf(__high2float(W0), p0.y, A0); \
  A0 = fmaf(__low2float(W1),  p0.z, A0); A0 = fmaf(__high2float(W1), p0.w, A0); \
  A0 = fmaf(__low2float(W2),  p1.x, A0); A0 = fmaf(__high2float(W2), p1.y, A0); \
  A0 = fmaf(__low2float(W3),  p1.z, A0); A0 = fmaf(__high2float(W3), p1.w, A0); \
  A1 = fmaf(__low2float(W0),  q0.x, A1); A1 = fmaf(__high2float(W0), q0.y, A1); \
  A1 = fmaf(__low2float(W1),  q0.z, A1); A1 = fmaf(__high2float(W1), q0.w, A1); \
  A1 = fmaf(__low2float(W2),  q1.x, A1); A1 = fmaf(__high2float(W2), q1.y, A1); \
  A1 = fmaf(__low2float(W3),  q1.z, A1); A1 = fmaf(__high2float(W3), q1.w, A1);

// tag-check + fp32 LDS-deposit for poll slot J (UJ: sampled u64 register)
#define POLLCHK(J, UJ) \
  if (pend & (1 << J)){ \
    if ((u32)(UJ >> 32) == tag){ \
      hlds[cdst[J]] = __uint_as_float((u32)UJ); \
      pend &= ~(1 << J); \
    } \
  }

// 8 LLC-direct samples of this lane's 8 poll slots (512 B stride per slot set)
#define ISSUE8(R0, R1, R2, R3, R4, R5, R6, R7) \
  asm volatile( \
    "global_load_dwordx2 %0, %8, off sc0 sc1\n\t" \
    "global_load_dwordx2 %1, %8, off offset:512 sc0 sc1\n\t" \
    "global_load_dwordx2 %2, %8, off offset:1024 sc0 sc1\n\t" \
    "global_load_dwordx2 %3, %8, off offset:1536 sc0 sc1\n\t" \
    "global_load_dwordx2 %4, %8, off offset:2048 sc0 sc1\n\t" \
    "global_load_dwordx2 %5, %8, off offset:2560 sc0 sc1\n\t" \
    "global_load_dwordx2 %6, %8, off offset:3072 sc0 sc1\n\t" \
    "global_load_dwordx2 %7, %8, off offset:3584 sc0 sc1" \
    : "=&v"(R0), "=&v"(R1), "=&v"(R2), "=&v"(R3), \
      "=&v"(R4), "=&v"(R5), "=&v"(R6), "=&v"(R7) \
    : "v"(src) : "memory")

// LLC-direct reload of slot J (exec-masked by the pend predicate)
#define RELOAD(J, UJ, OFS) \
  if (pend & (1 << J)){ \
    asm volatile("global_load_dwordx2 %0, %1, off offset:" OFS " sc0 sc1" \
                 : "=v"(UJ) : "v"(src) : "memory"); \
  }

__global__ void __launch_bounds__(NTHR, 1) lstm_kernel(
    const float* __restrict__ xin, const float* __restrict__ Wih,
    const float* __restrict__ Whh, const float* __restrict__ bih,
    const float* __restrict__ bhh, u64* __restrict__ chk,
    float* __restrict__ seqout)
{
  extern __shared__ char smem[];
  float* hlds = (float*)smem;                    // [2][2304] = 18432 B (padded h)
  float* pls  = (float*)(smem + 18432);          // [2][640]  =  5120 B partials
  float* bias = (float*)(smem + 23552);          // [32]

  const int tid  = threadIdx.x;
  const int blk  = blockIdx.x;
  const int e0   = blk << 3;                     // this block owns h elems e0..e0+7
  const int lane = tid & 63;
  const int wv   = tid >> 6;                     // wave 0..7, k-slice [wv*256, +256)
  const int rg   = lane >> 3;                    // row group: rows rg*4..rg*4+3
  const int ksl  = lane & 7;                     // 32-k sub-slice within wave
  const int ks   = (wv << 3) + ksl;              // global 32-k slice 0..63
  const int k0   = ks << 5;

  if (tid < 32){
    const int grow = ((tid >> 3) << 11) + e0 + (tid & 7);
    bias[tid] = bih[grow] + bhh[grow];
  }
  // x for t=0, written in the padded h layout
  for (int i = tid; i < 2 * E; i += NTHR){
    const int b = i >> 11, k = i & 2047;
    hlds[b * HLDS_B + (k >> 5) * 36 + (k & 31)] = xin[i];
  }
  __syncthreads();

  const float* hb0 = hlds + ks * 36;             // batch 0, own 32-k slice
  const float* hb1 = hlds + HLDS_B + ks * 36;    // batch 1

  // ---- fused: build f16 Wc = Wih + Whh into registers (64 half2) AND
  //      compute t=0 gates = x @ W_ih^T in full fp32 (h=0 at t=0) ----
  __half2 wh[64];
  float acc0[4] = {0.f, 0.f, 0.f, 0.f};
  float acc1[4] = {0.f, 0.f, 0.f, 0.f};
  #pragma unroll
  for (int rr = 0; rr < 4; ++rr){
    const int row  = (rg << 2) + rr;             // 0..31 = gate*8 + eoff
    const int grow = ((row >> 3) << 11) + e0 + (row & 7);
    const float* pa = Wih + (size_t)grow * E + k0;
    const float* pb = Whh + (size_t)grow * E + k0;
    #pragma unroll
    for (int c = 0; c < 8; ++c){                 // 4 k per chunk
      float4 a = *(const float4*)(pa + (c << 2));
      float4 b = *(const float4*)(pb + (c << 2));
      wh[(rr << 4) + (c << 1)    ] =
        __halves2half2(__float2half_rn(a.x + b.x), __float2half_rn(a.y + b.y));
      wh[(rr << 4) + (c << 1) + 1] =
        __halves2half2(__float2half_rn(a.z + b.z), __float2half_rn(a.w + b.w));
      float4 x0 = *(const float4*)(hb0 + (c << 2));
      float4 x1 = *(const float4*)(hb1 + (c << 2));
      acc0[rr] = fmaf(a.x, x0.x, acc0[rr]); acc0[rr] = fmaf(a.y, x0.y, acc0[rr]);
      acc0[rr] = fmaf(a.z, x0.z, acc0[rr]); acc0[rr] = fmaf(a.w, x0.w, acc0[rr]);
      acc1[rr] = fmaf(a.x, x1.x, acc1[rr]); acc1[rr] = fmaf(a.y, x1.y, acc1[rr]);
      acc1[rr] = fmaf(a.z, x1.z, acc1[rr]); acc1[rr] = fmaf(a.w, x1.w, acc1[rr]);
    }
  }

  const float br = bias[lane & 31];              // hoisted (used by wave 0)
  float creg = 0.0f;                             // cell state (producer lanes)

  // wave-local poll mapping: chunk c = wv*512 + j*64 + lane, so load j is a
  // 512 B contiguous wave read (full 64 B lines -> no fetch amplification).
  // chunk c (block-relative): b=(c>>3)&1, elem e=((c>>4)<<3)|(c&7)
  int cdst[8];
  #pragma unroll
  for (int j = 0; j < 8; ++j){
    const int c = (wv << 9) + (j << 6) + lane;
    const int b = (c >> 3) & 1;
    const int e = ((c >> 4) << 3) | (c & 7);
    cdst[j] = b * HLDS_B + (e >> 5) * 36 + (e & 31);
  }
  u64* const pchk0 = chk;                        // parity 0 base
  u64* const pchk1 = chk + 4096;                 // parity 1 base

  for (int t = 0; t < 2048; ++t){
    // wave-level pre-reduce across the 8 k-sub-slices (ksl = lane bits 0..2)
    #pragma unroll
    for (int m = 1; m <= 4; m <<= 1){
      #pragma unroll
      for (int rr = 0; rr < 4; ++rr){
        acc0[rr] += __shfl_xor(acc0[rr], m, 64);
        acc1[rr] += __shfl_xor(acc1[rr], m, 64);
      }
    }
    if (ksl == 0){                               // 8 lanes/wave publish partials
      float2* pw = (float2*)(pls + (t & 1) * PLS_PAR);
      #pragma unroll
      for (int rr = 0; rr < 4; ++rr)
        pw[((rg << 2) + rr) * (PLS_STRIDE / 2) + wv] = make_float2(acc0[rr], acc1[rr]);
    }
    __syncthreads();                             // the ONLY barrier per step

    if (wv == 0){                                // reduce 8 wave-partials + update
      const int r = lane & 31;
      const int b = lane >> 5;
      const float* rp = pls + (t & 1) * PLS_PAR + r * PLS_STRIDE;
      float4 v0 = *(const float4*)(rp);
      float4 v1 = *(const float4*)(rp + 4);
      float4 v2 = *(const float4*)(rp + 8);
      float4 v3 = *(const float4*)(rp + 12);
      float s = br + (b ? (v0.y + v0.w + v1.y + v1.w + v2.y + v2.w + v3.y + v3.w)
                        : (v0.x + v0.z + v1.x + v1.z + v2.x + v2.z + v3.x + v3.z));
      const float gi = s;
      const float gf = __shfl(s, (lane + 8)  & 63, 64);
      const float gg = __shfl(s, (lane + 16) & 63, 64);
      const float go = __shfl(s, (lane + 24) & 63, 64);
      if (r < 8){
        const float cn = sigf(gf) * creg + sigf(gi) * tanhfast(gg);
        const float hn = sigf(go) * tanhfast(cn);
        creg = cn;
        if (t < 2047){                           // publish FIRST (critical path)
          const u64 pk = ((u64)(u32)(t + 1) << 32) | (u64)__float_as_uint(hn);
          u64* dst = (((t + 1) & 1) ? pchk1 : pchk0) + (blk << 4) + (b << 3) + r;
          asm volatile("global_store_dwordx2 %0, %1, off sc0 sc1"
                       :: "v"(dst), "v"(pk) : "memory");
        }
        seqout[(((size_t)b << 11) + (size_t)t) * E + e0 + r] = hn;
      }
    }
    if (t == 2047) break;

    {   // poll: LLC-direct; v12 reorder: issue reloads BEFORE sleep so the
        // flight overlaps the sleep (round period max(RTT,sleep), not sum)
      const u64* src = (((t + 1) & 1) ? pchk1 : pchk0) + (wv << 9) + lane;
      const u32 tag = (u32)(t + 1);
      u64 a0_, a1_, a2_, a3_, a4_, a5_, a6_, a7_;
      ISSUE8(a0_, a1_, a2_, a3_, a4_, a5_, a6_, a7_);
      asm volatile("s_waitcnt vmcnt(0)" ::: "memory");
      int pend = 0xFF;
      while (true){
        POLLCHK(0, a0_) POLLCHK(1, a1_) POLLCHK(2, a2_) POLLCHK(3, a3_)
        POLLCHK(4, a4_) POLLCHK(5, a5_) POLLCHK(6, a6_) POLLCHK(7, a7_)
        if (pend == 0) break;
        RELOAD(0, a0_, "0")    RELOAD(1, a1_, "512")
        RELOAD(2, a2_, "1024") RELOAD(3, a3_, "1536")
        RELOAD(4, a4_, "2048") RELOAD(5, a5_, "2560")
        RELOAD(6, a6_, "3072") RELOAD(7, a7_, "3584")
        __builtin_amdgcn_s_sleep(1);
        asm volatile("s_waitcnt vmcnt(0)" ::: "memory");
      }
      // own ds_writes visible to all lanes of this wave (wave-synchronous)
      asm volatile("s_waitcnt lgkmcnt(0)" ::: "memory");
      __builtin_amdgcn_sched_barrier(0);
    }

    // compute acc(t+1): h @ Wc^T, weights in f16 registers
    #pragma unroll
    for (int rr = 0; rr < 4; ++rr){ acc0[rr] = 0.f; acc1[rr] = 0.f; }
    #pragma unroll
    for (int c8 = 0; c8 < 4; ++c8){              // 8 k per chunk
      float4 p0 = *(const float4*)(hb0 + (c8 << 3));
      float4 p1 = *(const float4*)(hb0 + (c8 << 3) + 4);
      float4 q0 = *(const float4*)(hb1 + (c8 << 3));
      float4 q1 = *(const float4*)(hb1 + (c8 << 3) + 4);
      #pragma unroll
      for (int rr = 0; rr < 4; ++rr){
        ROWFMA8(wh[(rr << 4) + (c8 << 2)],     wh[(rr << 4) + (c8 << 2) + 1],
                wh[(rr << 4) + (c8 << 2) + 2], wh[(rr << 4) + (c8 << 2) + 3],
                acc0[rr], acc1[rr]);
      }
    }
  }
}

// seq -> workspace copy (proj pair path reads a clean, never-written source)
__global__ void copy_kernel(const float* __restrict__ s, float* __restrict__ d)
{
  const size_t i = (((size_t)blockIdx.x << 8) + threadIdx.x) << 2;
  *(float4*)(d + i) = *(const float4*)(s + i);
}

// proj PAIR path: blocks 2b,2b+1 share rows 32b..32b+31 (f16-staged from
// the WS copy, 128 KB LDS); each block computes one 1024-col half.
// Wout traffic 4.3 -> 2.05 GB (the v10 binding term), all 256 CUs busy,
// per-thread LDS b128 issue = v10 (16384). 4 cols x 32 rows acc = 128 VGPR
// + 32 weight regs: fits the 256-thr (1 wave/SIMD) budget.
__global__ void __launch_bounds__(256, 1) proj_pair_kernel(
    const float* __restrict__ src, float* __restrict__ io,
    const float* __restrict__ Wout, const float* __restrict__ bout)
{
  extern __shared__ char smem[];
  u32* ah = (u32*)smem;                        // [32 rows][1024] half2 = 128 KB
  const int tid = threadIdx.x;
  const int blk = blockIdx.x;
  const size_t rbase = (size_t)(blk >> 1) * 32 * E;
  const int ch = (blk & 1) << 10;              // column-half base

  for (int idx = tid; idx < 32768; idx += 256){   // 32*2048 halves / 2
    const float2 v = *(const float2*)(src + rbase + ((size_t)idx << 1));
    ah[idx] = (u32)__half_as_ushort(__float2half_rn(v.x))
            | ((u32)__half_as_ushort(__float2half_rn(v.y)) << 16);
  }
  __syncthreads();

  const int n0 = ch + tid;                     // 4 cols: n0 + {0,256,512,768}
  const int n1 = n0 + 256;
  const int n2 = n0 + 512;
  const int n3 = n0 + 768;
  const float* wr0 = Wout + (size_t)n0 * E;
  const float* wr1 = Wout + (size_t)n1 * E;
  const float* wr2 = Wout + (size_t)n2 * E;
  const float* wr3 = Wout + (size_t)n3 * E;
  float acc0[32], acc1[32], acc2[32], acc3[32];
  #pragma unroll
  for (int m = 0; m < 32; ++m){
    acc0[m] = 0.0f; acc1[m] = 0.0f; acc2[m] = 0.0f; acc3[m] = 0.0f;
  }
  for (int kc = 0; kc < 256; ++kc){            // 8 k per iter
    const float4 a0v = *(const float4*)(wr0 + (kc << 3));
    const float4 a1v = *(const float4*)(wr0 + (kc << 3) + 4);
    const float4 b0v = *(const float4*)(wr1 + (kc << 3));
    const float4 b1v = *(const float4*)(wr1 + (kc << 3) + 4);
    const float4 c0v = *(const float4*)(wr2 + (kc << 3));
    const float4 c1v = *(const float4*)(wr2 + (kc << 3) + 4);
    const float4 d0v = *(const float4*)(wr3 + (kc << 3));
    const float4 d1v = *(const float4*)(wr3 + (kc << 3) + 4);
    const u32* hp = ah + (kc << 2);
    #pragma unroll
    for (int m = 0; m < 32; ++m){
      const uint4 hv = *(const uint4*)(hp + (m << 10));  // 8 halves, broadcast
      const __half2 h0 = __builtin_bit_cast(__half2, hv.x);
      const __half2 h1 = __builtin_bit_cast(__half2, hv.y);
      const __half2 h2 = __builtin_bit_cast(__half2, hv.z);
      const __half2 h3 = __builtin_bit_cast(__half2, hv.w);
      const float x0 = __low2float(h0), x1 = __high2float(h0);
      const float x2 = __low2float(h1), x3 = __high2float(h1);
      const float x4 = __low2float(h2), x5 = __high2float(h2);
      const float x6 = __low2float(h3), x7 = __high2float(h3);
      acc0[m] = fmaf(a0v.x, x0, acc0[m]); acc0[m] = fmaf(a0v.y, x1, acc0[m]);
      acc0[m] = fmaf(a0v.z, x2, acc0[m]); acc0[m] = fmaf(a0v.w, x3, acc0[m]);
      acc0[m] = fmaf(a1v.x, x4, acc0[m]); acc0[m] = fmaf(a1v.y, x5, acc0[m]);
      acc0[m] = fmaf(a1v.z, x6, acc0[m]); acc0[m] = fmaf(a1v.w, x7, acc0[m]);
      acc1[m] = fmaf(b0v.x, x0, acc1[m]); acc1[m] = fmaf(b0v.y, x1, acc1[m]);
      acc1[m] = fmaf(b0v.z, x2, acc1[m]); acc1[m] = fmaf(b0v.w, x3, acc1[m]);
      acc1[m] = fmaf(b1v.x, x4, acc1[m]); acc1[m] = fmaf(b1v.y, x5, acc1[m]);
      acc1[m] = fmaf(b1v.z, x6, acc1[m]); acc1[m] = fmaf(b1v.w, x7, acc1[m]);
      acc2[m] = fmaf(c0v.x, x0, acc2[m]); acc2[m] = fmaf(c0v.y, x1, acc2[m]);
      acc2[m] = fmaf(c0v.z, x2, acc2[m]); acc2[m] = fmaf(c0v.w, x3, acc2[m]);
      acc2[m] = fmaf(c1v.x, x4, acc2[m]); acc2[m] = fmaf(c1v.y, x5, acc2[m]);
      acc2[m] = fmaf(c1v.z, x6, acc2[m]); acc2[m] = fmaf(c1v.w, x7, acc2[m]);
      acc3[m] = fmaf(d0v.x, x0, acc3[m]); acc3[m] = fmaf(d0v.y, x1, acc3[m]);
      acc3[m] = fmaf(d0v.z, x2, acc3[m]); acc3[m] = fmaf(d0v.w, x3, acc3[m]);
      acc3[m] = fmaf(d1v.x, x4, acc3[m]); acc3[m] = fmaf(d1v.y, x5, acc3[m]);
      acc3[m] = fmaf(d1v.z, x6, acc3[m]); acc3[m] = fmaf(d1v.w, x7, acc3[m]);
    }
  }
  const float bo0 = bout[n0];
  const float bo1 = bout[n1];
  const float bo2 = bout[n2];
  const float bo3 = bout[n3];
  #pragma unroll
  for (int m = 0; m < 32; ++m){
    io[rbase + ((size_t)m << 11) + n0] = acc0[m] + bo0;
    io[rbase + ((size_t)m << 11) + n1] = acc1[m] + bo1;
    io[rbase + ((size_t)m << 11) + n2] = acc2[m] + bo2;
    io[rbase + ((size_t)m << 11) + n3] = acc3[m] + bo3;
  }
}

// Fallback (v10-proven): in-place, 16 rows f32-staged, 2 passes x 4 cols.
__global__ void __launch_bounds__(256, 1) proj_kernel(
    float* __restrict__ io, const float* __restrict__ Wout,
    const float* __restrict__ bout)
{
  extern __shared__ char smem[];
  float* alds = (float*)smem;                  // 16 x 2048 fp32 = 131072 B
  const int tid = threadIdx.x;
  const size_t rbase = (size_t)blockIdx.x * 16 * E;

  for (int idx = tid; idx < 8192; idx += 256){
    float4 v = *(const float4*)(io + rbase + ((size_t)idx << 2));
    *(float4*)(alds + (idx << 2)) = v;
  }
  __syncthreads();

  for (int p = 0; p < 2; ++p){
    const int n0 = (p << 10) + tid;
    const int n1 = n0 + 256;
    const int n2 = n0 + 512;
    const int n3 = n0 + 768;
    const float* wr0 = Wout + (size_t)n0 * E;
    const float* wr1 = Wout + (size_t)n1 * E;
    const float* wr2 = Wout + (size_t)n2 * E;
    const float* wr3 = Wout + (size_t)n3 * E;
    float acc0[16], acc1[16], acc2[16], acc3[16];
    #pragma unroll
    for (int m = 0; m < 16; ++m){
      acc0[m] = 0.0f; acc1[m] = 0.0f; acc2[m] = 0.0f; acc3[m] = 0.0f;
    }
    for (int kc = 0; kc < 256; ++kc){
      const float4 a0v = *(const float4*)(wr0 + (kc << 3));
      const float4 a1v = *(const float4*)(wr0 + (kc << 3) + 4);
      const float4 b0v = *(const float4*)(wr1 + (kc << 3));
      const float4 b1v = *(const float4*)(wr1 + (kc << 3) + 4);
      const float4 c0v = *(const float4*)(wr2 + (kc << 3));
      const float4 c1v = *(const float4*)(wr2 + (kc << 3) + 4);
      const float4 d0v = *(const float4*)(wr3 + (kc << 3));
      const float4 d1v = *(const float4*)(wr3 + (kc << 3) + 4);
      const float* ap = alds + (kc << 3);
      #pragma unroll
      for (int m = 0; m < 16; ++m){
        const float* a = ap + (m << 11);
        float4 x0 = *(const float4*)(a);
        float4 x1 = *(const float4*)(a + 4);
        acc0[m] = fmaf(a0v.x, x0.x, acc0[m]); acc0[m] = fmaf(a0v.y, x0.y, acc0[m]);
        acc0[m] = fmaf(a0v.z, x0.z, acc0[m]); acc0[m] = fmaf(a0v.w, x0.w, acc0[m]);
        acc0[m] = fmaf(a1v.x, x1.x, acc0[m]); acc0[m] = fmaf(a1v.y, x1.y, acc0[m]);
        acc0[m] = fmaf(a1v.z, x1.z, acc0[m]); acc0[m] = fmaf(a1v.w, x1.w, acc0[m]);
        acc1[m] = fmaf(b0v.x, x0.x, acc1[m]); acc1[m] = fmaf(b0v.y, x0.y, acc1[m]);
        acc1[m] = fmaf(b0v.z, x0.z, acc1[m]); acc1[m] = fmaf(b0v.w, x0.w, acc1[m]);
        acc1[m] = fmaf(b1v.x, x1.x, acc1[m]); acc1[m] = fmaf(b1v.y, x1.y, acc1[m]);
        acc1[m] = fmaf(b1v.z, x1.z, acc1[m]); acc1[m] = fmaf(b1v.w, x1.w, acc1[m]);
        acc2[m] = fmaf(c0v.x, x0.x, acc2[m]); acc2[m] = fmaf(c0v.y, x0.y, acc2[m]);
        acc2[m] = fmaf(c0v.z, x0.z, acc2[m]); acc2[m] = fmaf(c0v.w, x0.w, acc2[m]);
        acc2[m] = fmaf(c1v.x, x1.x, acc2[m]); acc2[m] = fmaf(c1v.y, x1.y, acc2[m]);
        acc2[m] = fmaf(c1v.z, x1.z, acc2[m]); acc2[m] = fmaf(c1v.w, x1.w, acc2[m]);
        acc3[m] = fmaf(d0v.x, x0.x, acc3[m]); acc3[m] = fmaf(d0v.y, x0.y, acc3[m]);
        acc3[m] = fmaf(d0v.z, x0.z, acc3[m]); acc3[m] = fmaf(d0v.w, x0.w, acc3[m]);
        acc3[m] = fmaf(d1v.x, x1.x, acc3[m]); acc3[m] = fmaf(d1v.y, x1.y, acc3[m]);
        acc3[m] = fmaf(d1v.z, x1.z, acc3[m]); acc3[m] = fmaf(d1v.w, x1.w, acc3[m]);
      }
    }
    const float bo0 = bout[n0];
    const float bo1 = bout[n1];
    const float bo2 = bout[n2];
    const float bo3 = bout[n3];
    #pragma unroll
    for (int m = 0; m < 16; ++m){
      io[rbase + ((size_t)m << 11) + n0] = acc0[m] + bo0;
      io[rbase + ((size_t)m << 11) + n1] = acc1[m] + bo1;
      io[rbase + ((size_t)m << 11) + n2] = acc2[m] + bo2;
      io[rbase + ((size_t)m << 11) + n3] = acc3[m] + bo3;
    }
  }
}

extern "C" void kernel_launch(void* const* d_in, const int* in_sizes, int n_in,
                              void* d_out, int out_size, void* d_ws, size_t ws_size,
                              hipStream_t stream)
{
  const float* xin  = (const float*)d_in[0];
  const float* Wih  = (const float*)d_in[1];
  const float* Whh  = (const float*)d_in[2];
  const float* bih  = (const float*)d_in[3];
  const float* bhh  = (const float*)d_in[4];
  const float* Wout = (const float*)d_in[5];
  const float* bout = (const float*)d_in[6];
  float* out = (float*)d_out;

  // chunk buffer: 2 parities x 4096 chunks x 8 B = 64 KB.
  // Poison 0xAAAAAAAA is never a valid tag (tags are 1..2047) -> no init pass.
  u64* chk = (u64*)d_ws;
  const size_t SEQ_BYTES = (size_t)2 * 2048 * E * sizeof(float);  // 33.5 MB

  hipFuncSetAttribute((const void*)lstm_kernel,
                      hipFuncAttributeMaxDynamicSharedMemorySize, SMEM_MAIN);
  hipFuncSetAttribute((const void*)proj_pair_kernel,
                      hipFuncAttributeMaxDynamicSharedMemorySize, SMEM_PROJ);
  hipFuncSetAttribute((const void*)proj_kernel,
                      hipFuncAttributeMaxDynamicSharedMemorySize, SMEM_PROJ);

  void* args[] = { (void*)&xin, (void*)&Wih, (void*)&Whh, (void*)&bih, (void*)&bhh,
                   (void*)&chk, (void*)&out };
  hipLaunchCooperativeKernel((const void*)lstm_kernel, dim3(NBLK), dim3(NTHR),
                             args, SMEM_MAIN, stream);

  if (ws_size >= 65536 + SEQ_BYTES){
    float* scp = (float*)((char*)d_ws + 65536);
    copy_kernel<<<8192, 256, 0, stream>>>(out, scp);   // 2M float4
    proj_pair_kernel<<<256, 256, SMEM_PROJ, stream>>>(scp, out, Wout, bout);
  } else {
    proj_kernel<<<256, 256, SMEM_PROJ, stream>>>(out, Wout, bout);
  }
}

// Round 12
// 8069.375 us; speedup vs baseline: 2.8787x; 1.0014x over previous
//
#include <hip/hip_runtime.h>
#include <hip/hip_fp16.h>
#include <stdint.h>

// LSTM, E=2048, B=2, T=2048, ALL I/O float32 (per reference dtypes).
// For t>=1 input==h, so gates = h @ (W_ih+W_hh)^T + (b_ih+b_hh).
// v13 = lstm: v12 unchanged (7447us best; poll-reorder kept, neutral)
//     + seq written DIRECTLY to workspace (no copy kernel, no in-place
//       race; lstm store cost identical, just a different dst pointer)
//     + proj: 256 blocks x 512 THREADS (2 waves/SIMD), 32 shared rows
//       f16-staged (128KB LDS), 2 cols/thread.
// v12 post-mortem: pair-proj at 1 wave/SIMD ran 2.05GB at only 3.4TB/s --
//   latency-bound (single wave can't hide LLC latency on the Wout stream;
//   v10's 4.3GB version was BW-saturated at 6.1TB/s). 2 waves/SIMD restores
//   latency hiding at the SAME halved traffic. FMA floor 218us overlapped.
// Weight-register law (v2/v7/v11): VGPR cap halves with waves/SIMD
//   (512thr->128, 1024thr->64). proj needs ~100 at 512thr: fits.
// Kept lstm (verified 4x): f16 packed weights in VGPRs (v_fma_mix), fp32 h
// in padded LDS (stride 36), wave-local poll slice, vmcnt(0)+sleep cadence
// with reloads-before-sleep, lgkmcnt-only deposit sync, ONE
// __syncthreads/step, wave0 tail with single coalesced 128B publish (v9
// law: publish must not fragment), c-state in registers, sc0 sc1
// LLC-direct exchange, publish-before-seqout. Protocol: 8B [tag|payload]
// chunks, tag-validated (poison 0xAAAAAAAA never matches tags 1..2047).

#define E 2048
#define NBLK 256
#define NTHR 512
#define HLDS_B 2304            // padded floats per batch: 64 slices * 36
#define PLS_STRIDE 20          // floats per row slot (16 used + 4 pad)
#define PLS_PAR 640            // floats per parity: 32 rows * 20
#define SMEM_MAIN 23680
#define SMEM_PROJ 131072

typedef uint32_t u32;
typedef unsigned long long u64;

__device__ __forceinline__ float sigf(float x){
  return __builtin_amdgcn_rcpf(1.0f + __expf(-x));
}
__device__ __forceinline__ float tanhfast(float x){
  // 1 - 2/(e^{2x}+1); exp overflow -> rcp(inf)=0 -> 1; underflow -> -1.
  float e = __expf(2.0f * x);
  return 1.0f - 2.0f * __builtin_amdgcn_rcpf(e + 1.0f);
}

// one row x 8 k, both batches: 16 FMAs from 4 packed-f16 weight pairs
#define ROWFMA8(W0, W1, W2, W3, A0, A1) \
  A0 = fmaf(__low2float(W0),  p0.x, A0); A0 = fmaf(__high2float(W0), p0.y, A0); \
  A0 = fmaf(__low2float(W1),  p0.z, A0); A0 = fmaf(__high2float(W1), p0.w, A0); \
  A0 = fmaf(__low2float(W2),  p1.x, A0); A0 = fmaf(__high2float(W2), p1.y, A0); \
  A0 = fmaf(__low2float(W3),  p1.z, A0); A0 = fmaf(__high2float(W3), p1.w, A0); \
  A1 = fmaf(__low2float(W0),  q0.x, A1); A1 = fmaf(__high2float(W0), q0.y, A1); \
  A1 = fmaf(__low2float(W1),  q0.z, A1); A1 = fmaf(__high2float(W1), q0.w, A1); \
  A1 = fmaf(__low2float(W2),  q1.x, A1); A1 = fmaf(__high2float(W2), q1.y, A1); \
  A1 = fmaf(__low2float(W3),  q1.z, A1); A1 = fmaf(__high2float(W3), q1.w, A1);

// tag-check + fp32 LDS-deposit for poll slot J (UJ: sampled u64 register)
#define POLLCHK(J, UJ) \
  if (pend & (1 << J)){ \
    if ((u32)(UJ >> 32) == tag){ \
      hlds[cdst[J]] = __uint_as_float((u32)UJ); \
      pend &= ~(1 << J); \
    } \
  }

// 8 LLC-direct samples of this lane's 8 poll slots (512 B stride per slot set)
#define ISSUE8(R0, R1, R2, R3, R4, R5, R6, R7) \
  asm volatile( \
    "global_load_dwordx2 %0, %8, off sc0 sc1\n\t" \
    "global_load_dwordx2 %1, %8, off offset:512 sc0 sc1\n\t" \
    "global_load_dwordx2 %2, %8, off offset:1024 sc0 sc1\n\t" \
    "global_load_dwordx2 %3, %8, off offset:1536 sc0 sc1\n\t" \
    "global_load_dwordx2 %4, %8, off offset:2048 sc0 sc1\n\t" \
    "global_load_dwordx2 %5, %8, off offset:2560 sc0 sc1\n\t" \
    "global_load_dwordx2 %6, %8, off offset:3072 sc0 sc1\n\t" \
    "global_load_dwordx2 %7, %8, off offset:3584 sc0 sc1" \
    : "=&v"(R0), "=&v"(R1), "=&v"(R2), "=&v"(R3), \
      "=&v"(R4), "=&v"(R5), "=&v"(R6), "=&v"(R7) \
    : "v"(src) : "memory")

// LLC-direct reload of slot J (exec-masked by the pend predicate)
#define RELOAD(J, UJ, OFS) \
  if (pend & (1 << J)){ \
    asm volatile("global_load_dwordx2 %0, %1, off offset:" OFS " sc0 sc1" \
                 : "=v"(UJ) : "v"(src) : "memory"); \
  }

__global__ void __launch_bounds__(NTHR, 1) lstm_kernel(
    const float* __restrict__ xin, const float* __restrict__ Wih,
    const float* __restrict__ Whh, const float* __restrict__ bih,
    const float* __restrict__ bhh, u64* __restrict__ chk,
    float* __restrict__ seqout)
{
  extern __shared__ char smem[];
  float* hlds = (float*)smem;                    // [2][2304] = 18432 B (padded h)
  float* pls  = (float*)(smem + 18432);          // [2][640]  =  5120 B partials
  float* bias = (float*)(smem + 23552);          // [32]

  const int tid  = threadIdx.x;
  const int blk  = blockIdx.x;
  const int e0   = blk << 3;                     // this block owns h elems e0..e0+7
  const int lane = tid & 63;
  const int wv   = tid >> 6;                     // wave 0..7, k-slice [wv*256, +256)
  const int rg   = lane >> 3;                    // row group: rows rg*4..rg*4+3
  const int ksl  = lane & 7;                     // 32-k sub-slice within wave
  const int ks   = (wv << 3) + ksl;              // global 32-k slice 0..63
  const int k0   = ks << 5;

  if (tid < 32){
    const int grow = ((tid >> 3) << 11) + e0 + (tid & 7);
    bias[tid] = bih[grow] + bhh[grow];
  }
  // x for t=0, written in the padded h layout
  for (int i = tid; i < 2 * E; i += NTHR){
    const int b = i >> 11, k = i & 2047;
    hlds[b * HLDS_B + (k >> 5) * 36 + (k & 31)] = xin[i];
  }
  __syncthreads();

  const float* hb0 = hlds + ks * 36;             // batch 0, own 32-k slice
  const float* hb1 = hlds + HLDS_B + ks * 36;    // batch 1

  // ---- fused: build f16 Wc = Wih + Whh into registers (64 half2) AND
  //      compute t=0 gates = x @ W_ih^T in full fp32 (h=0 at t=0) ----
  __half2 wh[64];
  float acc0[4] = {0.f, 0.f, 0.f, 0.f};
  float acc1[4] = {0.f, 0.f, 0.f, 0.f};
  #pragma unroll
  for (int rr = 0; rr < 4; ++rr){
    const int row  = (rg << 2) + rr;             // 0..31 = gate*8 + eoff
    const int grow = ((row >> 3) << 11) + e0 + (row & 7);
    const float* pa = Wih + (size_t)grow * E + k0;
    const float* pb = Whh + (size_t)grow * E + k0;
    #pragma unroll
    for (int c = 0; c < 8; ++c){                 // 4 k per chunk
      float4 a = *(const float4*)(pa + (c << 2));
      float4 b = *(const float4*)(pb + (c << 2));
      wh[(rr << 4) + (c << 1)    ] =
        __halves2half2(__float2half_rn(a.x + b.x), __float2half_rn(a.y + b.y));
      wh[(rr << 4) + (c << 1) + 1] =
        __halves2half2(__float2half_rn(a.z + b.z), __float2half_rn(a.w + b.w));
      float4 x0 = *(const float4*)(hb0 + (c << 2));
      float4 x1 = *(const float4*)(hb1 + (c << 2));
      acc0[rr] = fmaf(a.x, x0.x, acc0[rr]); acc0[rr] = fmaf(a.y, x0.y, acc0[rr]);
      acc0[rr] = fmaf(a.z, x0.z, acc0[rr]); acc0[rr] = fmaf(a.w, x0.w, acc0[rr]);
      acc1[rr] = fmaf(a.x, x1.x, acc1[rr]); acc1[rr] = fmaf(a.y, x1.y, acc1[rr]);
      acc1[rr] = fmaf(a.z, x1.z, acc1[rr]); acc1[rr] = fmaf(a.w, x1.w, acc1[rr]);
    }
  }

  const float br = bias[lane & 31];              // hoisted (used by wave 0)
  float creg = 0.0f;                             // cell state (producer lanes)

  // wave-local poll mapping: chunk c = wv*512 + j*64 + lane, so load j is a
  // 512 B contiguous wave read (full 64 B lines -> no fetch amplification).
  // chunk c (block-relative): b=(c>>3)&1, elem e=((c>>4)<<3)|(c&7)
  int cdst[8];
  #pragma unroll
  for (int j = 0; j < 8; ++j){
    const int c = (wv << 9) + (j << 6) + lane;
    const int b = (c >> 3) & 1;
    const int e = ((c >> 4) << 3) | (c & 7);
    cdst[j] = b * HLDS_B + (e >> 5) * 36 + (e & 31);
  }
  u64* const pchk0 = chk;                        // parity 0 base
  u64* const pchk1 = chk + 4096;                 // parity 1 base

  for (int t = 0; t < 2048; ++t){
    // wave-level pre-reduce across the 8 k-sub-slices (ksl = lane bits 0..2)
    #pragma unroll
    for (int m = 1; m <= 4; m <<= 1){
      #pragma unroll
      for (int rr = 0; rr < 4; ++rr){
        acc0[rr] += __shfl_xor(acc0[rr], m, 64);
        acc1[rr] += __shfl_xor(acc1[rr], m, 64);
      }
    }
    if (ksl == 0){                               // 8 lanes/wave publish partials
      float2* pw = (float2*)(pls + (t & 1) * PLS_PAR);
      #pragma unroll
      for (int rr = 0; rr < 4; ++rr)
        pw[((rg << 2) + rr) * (PLS_STRIDE / 2) + wv] = make_float2(acc0[rr], acc1[rr]);
    }
    __syncthreads();                             // the ONLY barrier per step

    if (wv == 0){                                // reduce 8 wave-partials + update
      const int r = lane & 31;
      const int b = lane >> 5;
      const float* rp = pls + (t & 1) * PLS_PAR + r * PLS_STRIDE;
      float4 v0 = *(const float4*)(rp);
      float4 v1 = *(const float4*)(rp + 4);
      float4 v2 = *(const float4*)(rp + 8);
      float4 v3 = *(const float4*)(rp + 12);
      float s = br + (b ? (v0.y + v0.w + v1.y + v1.w + v2.y + v2.w + v3.y + v3.w)
                        : (v0.x + v0.z + v1.x + v1.z + v2.x + v2.z + v3.x + v3.z));
      const float gi = s;
      const float gf = __shfl(s, (lane + 8)  & 63, 64);
      const float gg = __shfl(s, (lane + 16) & 63, 64);
      const float go = __shfl(s, (lane + 24) & 63, 64);
      if (r < 8){
        const float cn = sigf(gf) * creg + sigf(gi) * tanhfast(gg);
        const float hn = sigf(go) * tanhfast(cn);
        creg = cn;
        if (t < 2047){                           // publish FIRST (critical path)
          const u64 pk = ((u64)(u32)(t + 1) << 32) | (u64)__float_as_uint(hn);
          u64* dst = (((t + 1) & 1) ? pchk1 : pchk0) + (blk << 4) + (b << 3) + r;
          asm volatile("global_store_dwordx2 %0, %1, off sc0 sc1"
                       :: "v"(dst), "v"(pk) : "memory");
        }
        seqout[(((size_t)b << 11) + (size_t)t) * E + e0 + r] = hn;
      }
    }
    if (t == 2047) break;

    {   // poll: LLC-direct; reloads issued BEFORE sleep (flight overlaps)
      const u64* src = (((t + 1) & 1) ? pchk1 : pchk0) + (wv << 9) + lane;
      const u32 tag = (u32)(t + 1);
      u64 a0_, a1_, a2_, a3_, a4_, a5_, a6_, a7_;
      ISSUE8(a0_, a1_, a2_, a3_, a4_, a5_, a6_, a7_);
      asm volatile("s_waitcnt vmcnt(0)" ::: "memory");
      int pend = 0xFF;
      while (true){
        POLLCHK(0, a0_) POLLCHK(1, a1_) POLLCHK(2, a2_) POLLCHK(3, a3_)
        POLLCHK(4, a4_) POLLCHK(5, a5_) POLLCHK(6, a6_) POLLCHK(7, a7_)
        if (pend == 0) break;
        RELOAD(0, a0_, "0")    RELOAD(1, a1_, "512")
        RELOAD(2, a2_, "1024") RELOAD(3, a3_, "1536")
        RELOAD(4, a4_, "2048") RELOAD(5, a5_, "2560")
        RELOAD(6, a6_, "3072") RELOAD(7, a7_, "3584")
        __builtin_amdgcn_s_sleep(1);
        asm volatile("s_waitcnt vmcnt(0)" ::: "memory");
      }
      // own ds_writes visible to all lanes of this wave (wave-synchronous)
      asm volatile("s_waitcnt lgkmcnt(0)" ::: "memory");
      __builtin_amdgcn_sched_barrier(0);
    }

    // compute acc(t+1): h @ Wc^T, weights in f16 registers
    #pragma unroll
    for (int rr = 0; rr < 4; ++rr){ acc0[rr] = 0.f; acc1[rr] = 0.f; }
    #pragma unroll
    for (int c8 = 0; c8 < 4; ++c8){              // 8 k per chunk
      float4 p0 = *(const float4*)(hb0 + (c8 << 3));
      float4 p1 = *(const float4*)(hb0 + (c8 << 3) + 4);
      float4 q0 = *(const float4*)(hb1 + (c8 << 3));
      float4 q1 = *(const float4*)(hb1 + (c8 << 3) + 4);
      #pragma unroll
      for (int rr = 0; rr < 4; ++rr){
        ROWFMA8(wh[(rr << 4) + (c8 << 2)],     wh[(rr << 4) + (c8 << 2) + 1],
                wh[(rr << 4) + (c8 << 2) + 2], wh[(rr << 4) + (c8 << 2) + 3],
                acc0[rr], acc1[rr]);
      }
    }
  }
}

// proj PAIR path, 512 threads (2 waves/SIMD for latency hiding): blocks
// 2b,2b+1 share rows 32b..32b+31 (f16-staged from the WS seq, 128 KB LDS);
// each block computes one 1024-col half, 2 cols/thread. Wout traffic
// 4.3 -> 2.05 GB; 2 waves/SIMD hide LLC latency (v12's 1-wave version ran
// at 3.4 TB/s, latency-bound). acc 2x32=64 VGPR + ~36 temps < 128 cap.
__global__ void __launch_bounds__(512, 1) proj_pair_kernel(
    const float* __restrict__ src, float* __restrict__ io,
    const float* __restrict__ Wout, const float* __restrict__ bout)
{
  extern __shared__ char smem[];
  u32* ah = (u32*)smem;                        // [32 rows][1024] half2 = 128 KB
  const int tid = threadIdx.x;
  const int blk = blockIdx.x;
  const size_t rbase = (size_t)(blk >> 1) * 32 * E;
  const int ch = (blk & 1) << 10;              // column-half base

  for (int idx = tid; idx < 32768; idx += 512){   // 32*2048 halves / 2
    const float2 v = *(const float2*)(src + rbase + ((size_t)idx << 1));
    ah[idx] = (u32)__half_as_ushort(__float2half_rn(v.x))
            | ((u32)__half_as_ushort(__float2half_rn(v.y)) << 16);
  }
  __syncthreads();

  const int n0 = ch + tid;                     // 2 cols: n0, n0+512
  const int n1 = n0 + 512;
  const float* wr0 = Wout + (size_t)n0 * E;
  const float* wr1 = Wout + (size_t)n1 * E;
  float acc0[32], acc1[32];
  #pragma unroll
  for (int m = 0; m < 32; ++m){ acc0[m] = 0.0f; acc1[m] = 0.0f; }
  for (int kc = 0; kc < 256; ++kc){            // 8 k per iter
    const float4 a0v = *(const float4*)(wr0 + (kc << 3));
    const float4 a1v = *(const float4*)(wr0 + (kc << 3) + 4);
    const float4 b0v = *(const float4*)(wr1 + (kc << 3));
    const float4 b1v = *(const float4*)(wr1 + (kc << 3) + 4);
    const u32* hp = ah + (kc << 2);
    #pragma unroll
    for (int m = 0; m < 32; ++m){
      const uint4 hv = *(const uint4*)(hp + (m << 10));  // 8 halves, broadcast
      const __half2 h0 = __builtin_bit_cast(__half2, hv.x);
      const __half2 h1 = __builtin_bit_cast(__half2, hv.y);
      const __half2 h2 = __builtin_bit_cast(__half2, hv.z);
      const __half2 h3 = __builtin_bit_cast(__half2, hv.w);
      const float x0 = __low2float(h0), x1 = __high2float(h0);
      const float x2 = __low2float(h1), x3 = __high2float(h1);
      const float x4 = __low2float(h2), x5 = __high2float(h2);
      const float x6 = __low2float(h3), x7 = __high2float(h3);
      acc0[m] = fmaf(a0v.x, x0, acc0[m]); acc0[m] = fmaf(a0v.y, x1, acc0[m]);
      acc0[m] = fmaf(a0v.z, x2, acc0[m]); acc0[m] = fmaf(a0v.w, x3, acc0[m]);
      acc0[m] = fmaf(a1v.x, x4, acc0[m]); acc0[m] = fmaf(a1v.y, x5, acc0[m]);
      acc0[m] = fmaf(a1v.z, x6, acc0[m]); acc0[m] = fmaf(a1v.w, x7, acc0[m]);
      acc1[m] = fmaf(b0v.x, x0, acc1[m]); acc1[m] = fmaf(b0v.y, x1, acc1[m]);
      acc1[m] = fmaf(b0v.z, x2, acc1[m]); acc1[m] = fmaf(b0v.w, x3, acc1[m]);
      acc1[m] = fmaf(b1v.x, x4, acc1[m]); acc1[m] = fmaf(b1v.y, x5, acc1[m]);
      acc1[m] = fmaf(b1v.z, x6, acc1[m]); acc1[m] = fmaf(b1v.w, x7, acc1[m]);
    }
  }
  const float bo0 = bout[n0];
  const float bo1 = bout[n1];
  #pragma unroll
  for (int m = 0; m < 32; ++m){
    io[rbase + ((size_t)m << 11) + n0] = acc0[m] + bo0;
    io[rbase + ((size_t)m << 11) + n1] = acc1[m] + bo1;
  }
}

// Fallback (v10-proven, ws too small): in-place, 16 rows f32-staged,
// 2 passes x 4 cols.
__global__ void __launch_bounds__(256, 1) proj_kernel(
    float* __restrict__ io, const float* __restrict__ Wout,
    const float* __restrict__ bout)
{
  extern __shared__ char smem[];
  float* alds = (float*)smem;                  // 16 x 2048 fp32 = 131072 B
  const int tid = threadIdx.x;
  const size_t rbase = (size_t)blockIdx.x * 16 * E;

  for (int idx = tid; idx < 8192; idx += 256){
    float4 v = *(const float4*)(io + rbase + ((size_t)idx << 2));
    *(float4*)(alds + (idx << 2)) = v;
  }
  __syncthreads();

  for (int p = 0; p < 2; ++p){
    const int n0 = (p << 10) + tid;
    const int n1 = n0 + 256;
    const int n2 = n0 + 512;
    const int n3 = n0 + 768;
    const float* wr0 = Wout + (size_t)n0 * E;
    const float* wr1 = Wout + (size_t)n1 * E;
    const float* wr2 = Wout + (size_t)n2 * E;
    const float* wr3 = Wout + (size_t)n3 * E;
    float acc0[16], acc1[16], acc2[16], acc3[16];
    #pragma unroll
    for (int m = 0; m < 16; ++m){
      acc0[m] = 0.0f; acc1[m] = 0.0f; acc2[m] = 0.0f; acc3[m] = 0.0f;
    }
    for (int kc = 0; kc < 256; ++kc){
      const float4 a0v = *(const float4*)(wr0 + (kc << 3));
      const float4 a1v = *(const float4*)(wr0 + (kc << 3) + 4);
      const float4 b0v = *(const float4*)(wr1 + (kc << 3));
      const float4 b1v = *(const float4*)(wr1 + (kc << 3) + 4);
      const float4 c0v = *(const float4*)(wr2 + (kc << 3));
      const float4 c1v = *(const float4*)(wr2 + (kc << 3) + 4);
      const float4 d0v = *(const float4*)(wr3 + (kc << 3));
      const float4 d1v = *(const float4*)(wr3 + (kc << 3) + 4);
      const float* ap = alds + (kc << 3);
      #pragma unroll
      for (int m = 0; m < 16; ++m){
        const float* a = ap + (m << 11);
        float4 x0 = *(const float4*)(a);
        float4 x1 = *(const float4*)(a + 4);
        acc0[m] = fmaf(a0v.x, x0.x, acc0[m]); acc0[m] = fmaf(a0v.y, x0.y, acc0[m]);
        acc0[m] = fmaf(a0v.z, x0.z, acc0[m]); acc0[m] = fmaf(a0v.w, x0.w, acc0[m]);
        acc0[m] = fmaf(a1v.x, x1.x, acc0[m]); acc0[m] = fmaf(a1v.y, x1.y, acc0[m]);
        acc0[m] = fmaf(a1v.z, x1.z, acc0[m]); acc0[m] = fmaf(a1v.w, x1.w, acc0[m]);
        acc1[m] = fmaf(b0v.x, x0.x, acc1[m]); acc1[m] = fmaf(b0v.y, x0.y, acc1[m]);
        acc1[m] = fmaf(b0v.z, x0.z, acc1[m]); acc1[m] = fmaf(b0v.w, x0.w, acc1[m]);
        acc1[m] = fmaf(b1v.x, x1.x, acc1[m]); acc1[m] = fmaf(b1v.y, x1.y, acc1[m]);
        acc1[m] = fmaf(b1v.z, x1.z, acc1[m]); acc1[m] = fmaf(b1v.w, x1.w, acc1[m]);
        acc2[m] = fmaf(c0v.x, x0.x, acc2[m]); acc2[m] = fmaf(c0v.y, x0.y, acc2[m]);
        acc2[m] = fmaf(c0v.z, x0.z, acc2[m]); acc2[m] = fmaf(c0v.w, x0.w, acc2[m]);
        acc2[m] = fmaf(c1v.x, x1.x, acc2[m]); acc2[m] = fmaf(c1v.y, x1.y, acc2[m]);
        acc2[m] = fmaf(c1v.z, x1.z, acc2[m]); acc2[m] = fmaf(c1v.w, x1.w, acc2[m]);
        acc3[m] = fmaf(d0v.x, x0.x, acc3[m]); acc3[m] = fmaf(d0v.y, x0.y, acc3[m]);
        acc3[m] = fmaf(d0v.z, x0.z, acc3[m]); acc3[m] = fmaf(d0v.w, x0.w, acc3[m]);
        acc3[m] = fmaf(d1v.x, x1.x, acc3[m]); acc3[m] = fmaf(d1v.y, x1.y, acc3[m]);
        acc3[m] = fmaf(d1v.z, x1.z, acc3[m]); acc3[m] = fmaf(d1v.w, x1.w, acc3[m]);
      }
    }
    const float bo0 = bout[n0];
    const float bo1 = bout[n1];
    const float bo2 = bout[n2];
    const float bo3 = bout[n3];
    #pragma unroll
    for (int m = 0; m < 16; ++m){
      io[rbase + ((size_t)m << 11) + n0] = acc0[m] + bo0;
      io[rbase + ((size_t)m << 11) + n1] = acc1[m] + bo1;
      io[rbase + ((size_t)m << 11) + n2] = acc2[m] + bo2;
      io[rbase + ((size_t)m << 11) + n3] = acc3[m] + bo3;
    }
  }
}

extern "C" void kernel_launch(void* const* d_in, const int* in_sizes, int n_in,
                              void* d_out, int out_size, void* d_ws, size_t ws_size,
                              hipStream_t stream)
{
  const float* xin  = (const float*)d_in[0];
  const float* Wih  = (const float*)d_in[1];
  const float* Whh  = (const float*)d_in[2];
  const float* bih  = (const float*)d_in[3];
  const float* bhh  = (const float*)d_in[4];
  const float* Wout = (const float*)d_in[5];
  const float* bout = (const float*)d_in[6];
  float* out = (float*)d_out;

  // workspace: [0,64K) chunk buffer (2 parities x 4096 x 8 B; poison
  // 0xAAAAAAAA never matches tags 1..2047 -> no init pass);
  // [64K, 64K+33.5MB) seq staging (lstm writes seq here; proj reads it).
  u64* chk = (u64*)d_ws;
  const size_t SEQ_BYTES = (size_t)2 * 2048 * E * sizeof(float);  // 33.5 MB
  const bool big = ws_size >= 65536 + SEQ_BYTES;
  float* seqdst = big ? (float*)((char*)d_ws + 65536) : out;

  hipFuncSetAttribute((const void*)lstm_kernel,
                      hipFuncAttributeMaxDynamicSharedMemorySize, SMEM_MAIN);
  hipFuncSetAttribute((const void*)proj_pair_kernel,
                      hipFuncAttributeMaxDynamicSharedMemorySize, SMEM_PROJ);
  hipFuncSetAttribute((const void*)proj_kernel,
                      hipFuncAttributeMaxDynamicSharedMemorySize, SMEM_PROJ);

  void* args[] = { (void*)&xin, (void*)&Wih, (void*)&Whh, (void*)&bih, (void*)&bhh,
                   (void*)&chk, (void*)&seqdst };
  hipLaunchCooperativeKernel((const void*)lstm_kernel, dim3(NBLK), dim3(NTHR),
                             args, SMEM_MAIN, stream);

  if (big){
    proj_pair_kernel<<<256, 512, SMEM_PROJ, stream>>>(seqdst, out, Wout, bout);
  } else {
    proj_kernel<<<256, 256, SMEM_PROJ, stream>>>(out, Wout, bout);
  }
}

// Round 14
// 7714.304 us; speedup vs baseline: 3.0112x; 1.0460x over previous
//
#include <hip/hip_runtime.h>
#include <hip/hip_fp16.h>
#include <stdint.h>

// LSTM, E=2048, B=2, T=2048, ALL I/O float32 (per reference dtypes).
// For t>=1 input==h, so gates = h @ (W_ih+W_hh)^T + (b_ih+b_hh).
// v15 = v14 with the wout_cvt GRID FIXED: 2048 blocks (4,194,304 floats /
//   (256 thr x 8 floats)), not 4096 -- v14's extra 2048 blocks read 16.8MB
//   past Wout's end -> memory fault -> abort. All kernels else identical.
// v14 lstm: v13 + 16B chunks [pay_b0|tag|pay_b1|tag] (poll 4 dwordx4/lane,
//   HALF the fabric requests/round; publish still ONE coalesced 128B store
//   from 8 lanes; 8B halves self-validating under tearing) + parallel-gate
//   tail (each wave0 lane does its own gate's nonlinearity -> 3 shfl ->
//   cell lanes finish; transcendental depth 5->2; v11-validated).
// v14 proj: f16 Wout pre-pass into ws (one-shot quantization) +
//   v_dot2_f32_f16. Wout traffic 2.05->1.02GB, FMA issue 219->110us.
// Kept lstm (verified 5x): f16 packed weights in VGPRs (v_fma_mix), fp32 h
// in padded LDS (stride 36), wave-local poll slice, vmcnt(0)+sleep cadence
// with reloads-before-sleep (v6: pipelined no-sleep regresses), lgkmcnt-only
// deposit sync, ONE __syncthreads/step, wave0 tail with single coalesced
// publish (v9 law), c-state in registers, sc0 sc1 LLC-direct exchange,
// publish-before-seqout. Protocol: tag-validated chunks (poison 0xAAAAAAAA
// never matches tags 1..2047), relaxed, no fences.
// chk: [parity(2)][2048 chunks] x 16B = 64KB.

#define E 2048
#define NBLK 256
#define NTHR 512
#define HLDS_B 2304            // padded floats per batch: 64 slices * 36
#define PLS_STRIDE 20          // floats per row slot (16 used + 4 pad)
#define PLS_PAR 640            // floats per parity: 32 rows * 20
#define SMEM_MAIN 23680
#define SMEM_PROJ 131072

typedef uint32_t u32;
typedef unsigned long long u64;
typedef unsigned int u32x4 __attribute__((ext_vector_type(4)));
typedef _Float16 hf2 __attribute__((ext_vector_type(2)));

__device__ __forceinline__ float sigf(float x){
  return __builtin_amdgcn_rcpf(1.0f + __expf(-x));
}
__device__ __forceinline__ float tanhfast(float x){
  // 1 - 2/(e^{2x}+1); exp overflow -> rcp(inf)=0 -> 1; underflow -> -1.
  float e = __expf(2.0f * x);
  return 1.0f - 2.0f * __builtin_amdgcn_rcpf(e + 1.0f);
}
__device__ __forceinline__ u32 f16p(float lo, float hi){
  return (u32)__half_as_ushort(__float2half_rn(lo))
       | ((u32)__half_as_ushort(__float2half_rn(hi)) << 16);
}
__device__ __forceinline__ float dot2(u32 a, u32 b, float acc){
  return __builtin_amdgcn_fdot2(__builtin_bit_cast(hf2, a),
                                __builtin_bit_cast(hf2, b), acc, false);
}

// one row x 8 k, both batches: 16 FMAs from 4 packed-f16 weight pairs
#define ROWFMA8(W0, W1, W2, W3, A0, A1) \
  A0 = fmaf(__low2float(W0),  p0.x, A0); A0 = fmaf(__high2float(W0), p0.y, A0); \
  A0 = fmaf(__low2float(W1),  p0.z, A0); A0 = fmaf(__high2float(W1), p0.w, A0); \
  A0 = fmaf(__low2float(W2),  p1.x, A0); A0 = fmaf(__high2float(W2), p1.y, A0); \
  A0 = fmaf(__low2float(W3),  p1.z, A0); A0 = fmaf(__high2float(W3), p1.w, A0); \
  A1 = fmaf(__low2float(W0),  q0.x, A1); A1 = fmaf(__high2float(W0), q0.y, A1); \
  A1 = fmaf(__low2float(W1),  q0.z, A1); A1 = fmaf(__high2float(W1), q0.w, A1); \
  A1 = fmaf(__low2float(W2),  q1.x, A1); A1 = fmaf(__high2float(W2), q1.y, A1); \
  A1 = fmaf(__low2float(W3),  q1.z, A1); A1 = fmaf(__high2float(W3), q1.w, A1);

// tag-check both 8B halves of chunk slot J (QJ = [pay0,tag0,pay1,tag1])
#define CHKQ(J, QJ) \
  if (pend & (1 << (2*(J)))){ \
    if ((QJ).y == tag){ \
      hlds[cd0[J]] = __uint_as_float((QJ).x); pend &= ~(1 << (2*(J))); } } \
  if (pend & (2 << (2*(J)))){ \
    if ((QJ).w == tag){ \
      hlds[cd1[J]] = __uint_as_float((QJ).z); pend &= ~(2 << (2*(J))); } }

// 4 LLC-direct dwordx4 samples (1 KB contiguous per wave per load)
#define ISSUE4Q(Q0, Q1, Q2, Q3) \
  asm volatile( \
    "global_load_dwordx4 %0, %4, off sc0 sc1\n\t" \
    "global_load_dwordx4 %1, %4, off offset:1024 sc0 sc1\n\t" \
    "global_load_dwordx4 %2, %4, off offset:2048 sc0 sc1\n\t" \
    "global_load_dwordx4 %3, %4, off offset:3072 sc0 sc1" \
    : "=&v"(Q0), "=&v"(Q1), "=&v"(Q2), "=&v"(Q3) \
    : "v"(src) : "memory")

// exec-masked reload of chunk J if either half pending
#define RELOADQ(J, QJ, OFS) \
  if (pend & (3 << (2*(J)))){ \
    asm volatile("global_load_dwordx4 %0, %1, off offset:" OFS " sc0 sc1" \
                 : "=v"(QJ) : "v"(src) : "memory"); \
  }

__global__ void __launch_bounds__(NTHR, 1) lstm_kernel(
    const float* __restrict__ xin, const float* __restrict__ Wih,
    const float* __restrict__ Whh, const float* __restrict__ bih,
    const float* __restrict__ bhh, u32x4* __restrict__ chk16,
    float* __restrict__ seqout)
{
  extern __shared__ char smem[];
  float* hlds = (float*)smem;                    // [2][2304] = 18432 B (padded h)
  float* pls  = (float*)(smem + 18432);          // [2][640]  =  5120 B partials
  float* bias = (float*)(smem + 23552);          // [32]

  const int tid  = threadIdx.x;
  const int blk  = blockIdx.x;
  const int e0   = blk << 3;                     // this block owns h elems e0..e0+7
  const int lane = tid & 63;
  const int wv   = tid >> 6;                     // wave 0..7, k-slice [wv*256, +256)
  const int rg   = lane >> 3;                    // row group: rows rg*4..rg*4+3
  const int ksl  = lane & 7;                     // 32-k sub-slice within wave
  const int ks   = (wv << 3) + ksl;              // global 32-k slice 0..63
  const int k0   = ks << 5;

  if (tid < 32){
    const int grow = ((tid >> 3) << 11) + e0 + (tid & 7);
    bias[tid] = bih[grow] + bhh[grow];
  }
  // x for t=0, written in the padded h layout
  for (int i = tid; i < 2 * E; i += NTHR){
    const int b = i >> 11, k = i & 2047;
    hlds[b * HLDS_B + (k >> 5) * 36 + (k & 31)] = xin[i];
  }
  __syncthreads();

  const float* hb0 = hlds + ks * 36;             // batch 0, own 32-k slice
  const float* hb1 = hlds + HLDS_B + ks * 36;    // batch 1

  // ---- fused: build f16 Wc = Wih + Whh into registers (64 half2) AND
  //      compute t=0 gates = x @ W_ih^T in full fp32 (h=0 at t=0) ----
  __half2 wh[64];
  float acc0[4] = {0.f, 0.f, 0.f, 0.f};
  float acc1[4] = {0.f, 0.f, 0.f, 0.f};
  #pragma unroll
  for (int rr = 0; rr < 4; ++rr){
    const int row  = (rg << 2) + rr;             // 0..31 = gate*8 + eoff
    const int grow = ((row >> 3) << 11) + e0 + (row & 7);
    const float* pa = Wih + (size_t)grow * E + k0;
    const float* pb = Whh + (size_t)grow * E + k0;
    #pragma unroll
    for (int c = 0; c < 8; ++c){                 // 4 k per chunk
      float4 a = *(const float4*)(pa + (c << 2));
      float4 b = *(const float4*)(pb + (c << 2));
      wh[(rr << 4) + (c << 1)    ] =
        __halves2half2(__float2half_rn(a.x + b.x), __float2half_rn(a.y + b.y));
      wh[(rr << 4) + (c << 1) + 1] =
        __halves2half2(__float2half_rn(a.z + b.z), __float2half_rn(a.w + b.w));
      float4 x0 = *(const float4*)(hb0 + (c << 2));
      float4 x1 = *(const float4*)(hb1 + (c << 2));
      acc0[rr] = fmaf(a.x, x0.x, acc0[rr]); acc0[rr] = fmaf(a.y, x0.y, acc0[rr]);
      acc0[rr] = fmaf(a.z, x0.z, acc0[rr]); acc0[rr] = fmaf(a.w, x0.w, acc0[rr]);
      acc1[rr] = fmaf(a.x, x1.x, acc1[rr]); acc1[rr] = fmaf(a.y, x1.y, acc1[rr]);
      acc1[rr] = fmaf(a.z, x1.z, acc1[rr]); acc1[rr] = fmaf(a.w, x1.w, acc1[rr]);
    }
  }

  const float br = bias[lane & 31];              // hoisted (used by wave 0)
  float creg = 0.0f;                             // cell state (cell lanes)

  // poll mapping: chunk c == element e; wave wv polls its own k-slice
  // [wv*256, +256): 4 chunks/lane, each load = 1 KB contiguous per wave.
  int cd0[4], cd1[4];
  #pragma unroll
  for (int j = 0; j < 4; ++j){
    const int e = (wv << 8) + (j << 6) + lane;
    cd0[j] = (e >> 5) * 36 + (e & 31);           // batch 0 deposit
    cd1[j] = HLDS_B + cd0[j];                    // batch 1 deposit
  }

  for (int t = 0; t < 2048; ++t){
    // wave-level pre-reduce across the 8 k-sub-slices (ksl = lane bits 0..2)
    #pragma unroll
    for (int m = 1; m <= 4; m <<= 1){
      #pragma unroll
      for (int rr = 0; rr < 4; ++rr){
        acc0[rr] += __shfl_xor(acc0[rr], m, 64);
        acc1[rr] += __shfl_xor(acc1[rr], m, 64);
      }
    }
    if (ksl == 0){                               // 8 lanes/wave publish partials
      float2* pw = (float2*)(pls + (t & 1) * PLS_PAR);
      #pragma unroll
      for (int rr = 0; rr < 4; ++rr)
        pw[((rg << 2) + rr) * (PLS_STRIDE / 2) + wv] = make_float2(acc0[rr], acc1[rr]);
    }
    __syncthreads();                             // the ONLY barrier per step

    if (wv == 0){                                // parallel-gate tail (v11-style)
      const int r = lane & 31;                   // row = gate*8 + eoff
      const int b = lane >> 5;
      const float* rp = pls + (t & 1) * PLS_PAR + r * PLS_STRIDE;
      float4 v0 = *(const float4*)(rp);
      float4 v1 = *(const float4*)(rp + 4);
      float4 v2 = *(const float4*)(rp + 8);
      float4 v3 = *(const float4*)(rp + 12);
      float s = br + (b ? (v0.y + v0.w + v1.y + v1.w + v2.y + v2.w + v3.y + v3.w)
                        : (v0.x + v0.z + v1.x + v1.z + v2.x + v2.z + v3.x + v3.z));
      // own gate's nonlinearity in parallel: tanh(s) = 2*sig(2s)-1 (g==2)
      const int g = r >> 3;                      // 0=i, 1=f, 2=g, 3=o
      const float arg = (g == 2) ? (s + s) : s;
      const float t0v = sigf(arg);
      const float nl  = (g == 2) ? (2.0f * t0v - 1.0f) : t0v;
      const float SF = __shfl(nl, (lane + 8)  & 63, 64);   // sig(f) to cell lanes
      const float TG = __shfl(nl, (lane + 16) & 63, 64);   // tanh(g)
      const float SO = __shfl(nl, (lane + 24) & 63, 64);   // sig(o)
      if (r < 8){                                // cell lanes (g==0: nl=sig(i))
        const float cn = SF * creg + nl * TG;
        const float hn = SO * tanhfast(cn);
        creg = cn;
        const u32 h32 = __float_as_uint(hn);
        const u32 oth = (u32)__shfl((int)h32, (lane + 32) & 63, 64);  // b1 value
        if (t < 2047 && b == 0){                 // publish: ONE 128B store
          const u32 tg = (u32)(t + 1);
          u32x4 pk; pk.x = h32; pk.y = tg; pk.z = oth; pk.w = tg;
          u32x4* dst = chk16 + (((t + 1) & 1) << 11) + e0 + lane;
          asm volatile("global_store_dwordx4 %0, %1, off sc0 sc1"
                       :: "v"(dst), "v"(pk) : "memory");
        }
        seqout[(((size_t)b << 11) + (size_t)t) * E + e0 + r] = hn;
      }
    }
    if (t == 2047) break;

    {   // poll: LLC-direct 4x dwordx4; reloads issued BEFORE sleep
      const u32x4* src = (const u32x4*)chk16 + (((t + 1) & 1) << 11)
                       + (wv << 8) + lane;
      const u32 tag = (u32)(t + 1);
      u32x4 q0, q1, q2, q3;
      ISSUE4Q(q0, q1, q2, q3);
      asm volatile("s_waitcnt vmcnt(0)" ::: "memory");
      int pend = 0xFF;
      while (true){
        CHKQ(0, q0) CHKQ(1, q1) CHKQ(2, q2) CHKQ(3, q3)
        if (pend == 0) break;
        RELOADQ(0, q0, "0")    RELOADQ(1, q1, "1024")
        RELOADQ(2, q2, "2048") RELOADQ(3, q3, "3072")
        __builtin_amdgcn_s_sleep(1);
        asm volatile("s_waitcnt vmcnt(0)" ::: "memory");
      }
      // own ds_writes visible to all lanes of this wave (wave-synchronous)
      asm volatile("s_waitcnt lgkmcnt(0)" ::: "memory");
      __builtin_amdgcn_sched_barrier(0);
    }

    // compute acc(t+1): h @ Wc^T, weights in f16 registers
    #pragma unroll
    for (int rr = 0; rr < 4; ++rr){ acc0[rr] = 0.f; acc1[rr] = 0.f; }
    #pragma unroll
    for (int c8 = 0; c8 < 4; ++c8){              // 8 k per chunk
      float4 p0 = *(const float4*)(hb0 + (c8 << 3));
      float4 p1 = *(const float4*)(hb0 + (c8 << 3) + 4);
      float4 q0 = *(const float4*)(hb1 + (c8 << 3));
      float4 q1 = *(const float4*)(hb1 + (c8 << 3) + 4);
      #pragma unroll
      for (int rr = 0; rr < 4; ++rr){
        ROWFMA8(wh[(rr << 4) + (c8 << 2)],     wh[(rr << 4) + (c8 << 2) + 1],
                wh[(rr << 4) + (c8 << 2) + 2], wh[(rr << 4) + (c8 << 2) + 3],
                acc0[rr], acc1[rr]);
      }
    }
  }
}

// Wout f32 -> packed f16 (one-shot pre-pass into workspace).
// Grid: E*E / (256*8) = 2048 blocks EXACTLY (v14 launched 4096 -> OOB read).
__global__ void wout_cvt(const float* __restrict__ w, u32* __restrict__ o)
{
  const size_t i = (((size_t)blockIdx.x << 8) + threadIdx.x) << 3;  // 8 floats
  float4 a = *(const float4*)(w + i);
  float4 b = *(const float4*)(w + i + 4);
  uint4 r;
  r.x = f16p(a.x, a.y); r.y = f16p(a.z, a.w);
  r.z = f16p(b.x, b.y); r.w = f16p(b.z, b.w);
  *(uint4*)(o + (i >> 1)) = r;
}

// proj PAIR path, f16 Wout + v_dot2: blocks 2b,2b+1 share rows 32b..+31
// (f16-staged from WS seq, 128 KB LDS); block computes one 1024-col half,
// 2 cols/thread. Wout reads 1.02 GB (f16); dot2 halves FMA issue (219->
// 110us chip-wide). 512 thr = 2 waves/SIMD for latency hiding.
__global__ void __launch_bounds__(512, 1) proj_pair16(
    const float* __restrict__ src, float* __restrict__ io,
    const u32* __restrict__ wf, const float* __restrict__ bout)
{
  extern __shared__ char smem[];
  u32* ah = (u32*)smem;                        // [32 rows][1024] half2 = 128 KB
  const int tid = threadIdx.x;
  const int blk = blockIdx.x;
  const size_t rbase = (size_t)(blk >> 1) * 32 * E;
  const int ch = (blk & 1) << 10;              // column-half base

  for (int idx = tid; idx < 32768; idx += 512){   // 32*2048 halves / 2
    const float2 v = *(const float2*)(src + rbase + ((size_t)idx << 1));
    ah[idx] = f16p(v.x, v.y);
  }
  __syncthreads();

  const int n0 = ch + tid;                     // 2 cols: n0, n0+512
  const int n1 = n0 + 512;
  const u32* wr0 = wf + (size_t)n0 * 1024;     // 1024 u32 (2048 halves) per row
  const u32* wr1 = wf + (size_t)n1 * 1024;
  float acc0[32], acc1[32];
  #pragma unroll
  for (int m = 0; m < 32; ++m){ acc0[m] = 0.0f; acc1[m] = 0.0f; }
  for (int kc = 0; kc < 256; ++kc){            // 8 k per iter
    const uint4 wa = *(const uint4*)(wr0 + (kc << 2));
    const uint4 wb = *(const uint4*)(wr1 + (kc << 2));
    const u32* hp = ah + (kc << 2);
    #pragma unroll
    for (int m = 0; m < 32; ++m){
      const uint4 hv = *(const uint4*)(hp + (m << 10));  // 8 halves, broadcast
      acc0[m] = dot2(wa.x, hv.x, acc0[m]);
      acc0[m] = dot2(wa.y, hv.y, acc0[m]);
      acc0[m] = dot2(wa.z, hv.z, acc0[m]);
      acc0[m] = dot2(wa.w, hv.w, acc0[m]);
      acc1[m] = dot2(wb.x, hv.x, acc1[m]);
      acc1[m] = dot2(wb.y, hv.y, acc1[m]);
      acc1[m] = dot2(wb.z, hv.z, acc1[m]);
      acc1[m] = dot2(wb.w, hv.w, acc1[m]);
    }
  }
  const float bo0 = bout[n0];
  const float bo1 = bout[n1];
  #pragma unroll
  for (int m = 0; m < 32; ++m){
    io[rbase + ((size_t)m << 11) + n0] = acc0[m] + bo0;
    io[rbase + ((size_t)m << 11) + n1] = acc1[m] + bo1;
  }
}

// Fallback 1 (v13-proven): pair path, f32 Wout.
__global__ void __launch_bounds__(512, 1) proj_pair_kernel(
    const float* __restrict__ src, float* __restrict__ io,
    const float* __restrict__ Wout, const float* __restrict__ bout)
{
  extern __shared__ char smem[];
  u32* ah = (u32*)smem;
  const int tid = threadIdx.x;
  const int blk = blockIdx.x;
  const size_t rbase = (size_t)(blk >> 1) * 32 * E;
  const int ch = (blk & 1) << 10;

  for (int idx = tid; idx < 32768; idx += 512){
    const float2 v = *(const float2*)(src + rbase + ((size_t)idx << 1));
    ah[idx] = f16p(v.x, v.y);
  }
  __syncthreads();

  const int n0 = ch + tid;
  const int n1 = n0 + 512;
  const float* wr0 = Wout + (size_t)n0 * E;
  const float* wr1 = Wout + (size_t)n1 * E;
  float acc0[32], acc1[32];
  #pragma unroll
  for (int m = 0; m < 32; ++m){ acc0[m] = 0.0f; acc1[m] = 0.0f; }
  for (int kc = 0; kc < 256; ++kc){
    const float4 a0v = *(const float4*)(wr0 + (kc << 3));
    const float4 a1v = *(const float4*)(wr0 + (kc << 3) + 4);
    const float4 b0v = *(const float4*)(wr1 + (kc << 3));
    const float4 b1v = *(const float4*)(wr1 + (kc << 3) + 4);
    const u32* hp = ah + (kc << 2);
    #pragma unroll
    for (int m = 0; m < 32; ++m){
      const uint4 hv = *(const uint4*)(hp + (m << 10));
      const __half2 h0 = __builtin_bit_cast(__half2, hv.x);
      const __half2 h1 = __builtin_bit_cast(__half2, hv.y);
      const __half2 h2 = __builtin_bit_cast(__half2, hv.z);
      const __half2 h3 = __builtin_bit_cast(__half2, hv.w);
      const float x0 = __low2float(h0), x1 = __high2float(h0);
      const float x2 = __low2float(h1), x3 = __high2float(h1);
      const float x4 = __low2float(h2), x5 = __high2float(h2);
      const float x6 = __low2float(h3), x7 = __high2float(h3);
      acc0[m] = fmaf(a0v.x, x0, acc0[m]); acc0[m] = fmaf(a0v.y, x1, acc0[m]);
      acc0[m] = fmaf(a0v.z, x2, acc0[m]); acc0[m] = fmaf(a0v.w, x3, acc0[m]);
      acc0[m] = fmaf(a1v.x, x4, acc0[m]); acc0[m] = fmaf(a1v.y, x5, acc0[m]);
      acc0[m] = fmaf(a1v.z, x6, acc0[m]); acc0[m] = fmaf(a1v.w, x7, acc0[m]);
      acc1[m] = fmaf(b0v.x, x0, acc1[m]); acc1[m] = fmaf(b0v.y, x1, acc1[m]);
      acc1[m] = fmaf(b0v.z, x2, acc1[m]); acc1[m] = fmaf(b0v.w, x3, acc1[m]);
      acc1[m] = fmaf(b1v.x, x4, acc1[m]); acc1[m] = fmaf(b1v.y, x5, acc1[m]);
      acc1[m] = fmaf(b1v.z, x6, acc1[m]); acc1[m] = fmaf(b1v.w, x7, acc1[m]);
    }
  }
  const float bo0 = bout[n0];
  const float bo1 = bout[n1];
  #pragma unroll
  for (int m = 0; m < 32; ++m){
    io[rbase + ((size_t)m << 11) + n0] = acc0[m] + bo0;
    io[rbase + ((size_t)m << 11) + n1] = acc1[m] + bo1;
  }
}

// Fallback 2 (v10-proven, tiny ws): in-place, 16 rows f32-staged.
__global__ void __launch_bounds__(256, 1) proj_kernel(
    float* __restrict__ io, const float* __restrict__ Wout,
    const float* __restrict__ bout)
{
  extern __shared__ char smem[];
  float* alds = (float*)smem;
  const int tid = threadIdx.x;
  const size_t rbase = (size_t)blockIdx.x * 16 * E;

  for (int idx = tid; idx < 8192; idx += 256){
    float4 v = *(const float4*)(io + rbase + ((size_t)idx << 2));
    *(float4*)(alds + (idx << 2)) = v;
  }
  __syncthreads();

  for (int p = 0; p < 2; ++p){
    const int n0 = (p << 10) + tid;
    const int n1 = n0 + 256;
    const int n2 = n0 + 512;
    const int n3 = n0 + 768;
    const float* wr0 = Wout + (size_t)n0 * E;
    const float* wr1 = Wout + (size_t)n1 * E;
    const float* wr2 = Wout + (size_t)n2 * E;
    const float* wr3 = Wout + (size_t)n3 * E;
    float acc0[16], acc1[16], acc2[16], acc3[16];
    #pragma unroll
    for (int m = 0; m < 16; ++m){
      acc0[m] = 0.0f; acc1[m] = 0.0f; acc2[m] = 0.0f; acc3[m] = 0.0f;
    }
    for (int kc = 0; kc < 256; ++kc){
      const float4 a0v = *(const float4*)(wr0 + (kc << 3));
      const float4 a1v = *(const float4*)(wr0 + (kc << 3) + 4);
      const float4 b0v = *(const float4*)(wr1 + (kc << 3));
      const float4 b1v = *(const float4*)(wr1 + (kc << 3) + 4);
      const float4 c0v = *(const float4*)(wr2 + (kc << 3));
      const float4 c1v = *(const float4*)(wr2 + (kc << 3) + 4);
      const float4 d0v = *(const float4*)(wr3 + (kc << 3));
      const float4 d1v = *(const float4*)(wr3 + (kc << 3) + 4);
      const float* ap = alds + (kc << 3);
      #pragma unroll
      for (int m = 0; m < 16; ++m){
        const float* a = ap + (m << 11);
        float4 x0 = *(const float4*)(a);
        float4 x1 = *(const float4*)(a + 4);
        acc0[m] = fmaf(a0v.x, x0.x, acc0[m]); acc0[m] = fmaf(a0v.y, x0.y, acc0[m]);
        acc0[m] = fmaf(a0v.z, x0.z, acc0[m]); acc0[m] = fmaf(a0v.w, x0.w, acc0[m]);
        acc0[m] = fmaf(a1v.x, x1.x, acc0[m]); acc0[m] = fmaf(a1v.y, x1.y, acc0[m]);
        acc0[m] = fmaf(a1v.z, x1.z, acc0[m]); acc0[m] = fmaf(a1v.w, x1.w, acc0[m]);
        acc1[m] = fmaf(b0v.x, x0.x, acc1[m]); acc1[m] = fmaf(b0v.y, x0.y, acc1[m]);
        acc1[m] = fmaf(b0v.z, x0.z, acc1[m]); acc1[m] = fmaf(b0v.w, x0.w, acc1[m]);
        acc1[m] = fmaf(b1v.x, x1.x, acc1[m]); acc1[m] = fmaf(b1v.y, x1.y, acc1[m]);
        acc1[m] = fmaf(b1v.z, x1.z, acc1[m]); acc1[m] = fmaf(b1v.w, x1.w, acc1[m]);
        acc2[m] = fmaf(c0v.x, x0.x, acc2[m]); acc2[m] = fmaf(c0v.y, x0.y, acc2[m]);
        acc2[m] = fmaf(c0v.z, x0.z, acc2[m]); acc2[m] = fmaf(c0v.w, x0.w, acc2[m]);
        acc2[m] = fmaf(c1v.x, x1.x, acc2[m]); acc2[m] = fmaf(c1v.y, x1.y, acc2[m]);
        acc2[m] = fmaf(c1v.z, x1.z, acc2[m]); acc2[m] = fmaf(c1v.w, x1.w, acc2[m]);
        acc3[m] = fmaf(d0v.x, x0.x, acc3[m]); acc3[m] = fmaf(d0v.y, x0.y, acc3[m]);
        acc3[m] = fmaf(d0v.z, x0.z, acc3[m]); acc3[m] = fmaf(d0v.w, x0.w, acc3[m]);
        acc3[m] = fmaf(d1v.x, x1.x, acc3[m]); acc3[m] = fmaf(d1v.y, x1.y, acc3[m]);
        acc3[m] = fmaf(d1v.z, x1.z, acc3[m]); acc3[m] = fmaf(d1v.w, x1.w, acc3[m]);
      }
    }
    const float bo0 = bout[n0];
    const float bo1 = bout[n1];
    const float bo2 = bout[n2];
    const float bo3 = bout[n3];
    #pragma unroll
    for (int m = 0; m < 16; ++m){
      io[rbase + ((size_t)m << 11) + n0] = acc0[m] + bo0;
      io[rbase + ((size_t)m << 11) + n1] = acc1[m] + bo1;
      io[rbase + ((size_t)m << 11) + n2] = acc2[m] + bo2;
      io[rbase + ((size_t)m << 11) + n3] = acc3[m] + bo3;
    }
  }
}

extern "C" void kernel_launch(void* const* d_in, const int* in_sizes, int n_in,
                              void* d_out, int out_size, void* d_ws, size_t ws_size,
                              hipStream_t stream)
{
  const float* xin  = (const float*)d_in[0];
  const float* Wih  = (const float*)d_in[1];
  const float* Whh  = (const float*)d_in[2];
  const float* bih  = (const float*)d_in[3];
  const float* bhh  = (const float*)d_in[4];
  const float* Wout = (const float*)d_in[5];
  const float* bout = (const float*)d_in[6];
  float* out = (float*)d_out;

  // workspace: [0,64K) chunk buffer (2 parities x 2048 x 16 B; poison
  // 0xAAAAAAAA never matches tags 1..2047 -> no init pass);
  // [64K, +33.5MB) seq staging; [64K+SEQ, +8.4MB) f16 Wout.
  u32x4* chk16 = (u32x4*)d_ws;
  const size_t SEQ_BYTES = (size_t)2 * 2048 * E * sizeof(float);    // 33.55 MB
  const size_t WF_BYTES  = (size_t)E * E * 2;                       // 8.39 MB
  const bool big  = ws_size >= 65536 + SEQ_BYTES;
  const bool big2 = ws_size >= 65536 + SEQ_BYTES + WF_BYTES;
  float* seqdst = big ? (float*)((char*)d_ws + 65536) : out;
  u32*   wf     = (u32*)((char*)d_ws + 65536 + SEQ_BYTES);

  hipFuncSetAttribute((const void*)lstm_kernel,
                      hipFuncAttributeMaxDynamicSharedMemorySize, SMEM_MAIN);
  hipFuncSetAttribute((const void*)proj_pair16,
                      hipFuncAttributeMaxDynamicSharedMemorySize, SMEM_PROJ);
  hipFuncSetAttribute((const void*)proj_pair_kernel,
                      hipFuncAttributeMaxDynamicSharedMemorySize, SMEM_PROJ);
  hipFuncSetAttribute((const void*)proj_kernel,
                      hipFuncAttributeMaxDynamicSharedMemorySize, SMEM_PROJ);

  if (big2){
    // E*E = 4,194,304 floats / (256 thr x 8 floats) = 2048 blocks exactly
    wout_cvt<<<2048, 256, 0, stream>>>(Wout, wf);
  }

  void* args[] = { (void*)&xin, (void*)&Wih, (void*)&Whh, (void*)&bih, (void*)&bhh,
                   (void*)&chk16, (void*)&seqdst };
  hipLaunchCooperativeKernel((const void*)lstm_kernel, dim3(NBLK), dim3(NTHR),
                             args, SMEM_MAIN, stream);

  if (big2){
    proj_pair16<<<256, 512, SMEM_PROJ, stream>>>(seqdst, out, wf, bout);
  } else if (big){
    proj_pair_kernel<<<256, 512, SMEM_PROJ, stream>>>(seqdst, out, Wout, bout);
  } else {
    proj_kernel<<<256, 256, SMEM_PROJ, stream>>>(out, Wout, bout);
  }
}